// Round 2
// baseline (9147.283 us; speedup 1.0000x reference)
//
#include <hip/hip_runtime.h>
#include <math.h>

#define B_ 8
#define L_ 16384
#define C_ 128
#define H_ 4
#define WS_ 64
#define SHIFT_ 32
#define NW_ 256
#define HD_ 32
#define HID_ 512
#define M_ (B_*L_)            // 131072 rows
#define SCALE_ 0.17677669529663687f
#define EPS_ 1e-5f

// ---------------------------------------------------------------------------
// LayerNorm (optionally with cyclic shift on the source index).
// One wave per row; 4 rows per 256-thread block. Reads global rows
// (m_off + local), writes LOCAL rows (chunked workspace).
// ---------------------------------------------------------------------------
__global__ __launch_bounds__(256)
void ln_kernel(const float* __restrict__ in, float* __restrict__ out,
               const float* __restrict__ gamma, const float* __restrict__ beta,
               int do_shift, int m_off)
{
    int m    = blockIdx.x * 4 + (threadIdx.x >> 6);   // local row
    int lane = threadIdx.x & 63;
    int gr   = m_off + m;                             // global row
    int src  = gr;
    if (do_shift) {
        int b = gr >> 14, l = gr & (L_ - 1);
        src = (b << 14) | ((l + SHIFT_) & (L_ - 1));
    }
    const float* row = in + (size_t)src * C_;
    float2 v = *(const float2*)&row[lane * 2];
    float s  = v.x + v.y;
    float ss = v.x * v.x + v.y * v.y;
#pragma unroll
    for (int off = 1; off < 64; off <<= 1) {
        s  += __shfl_xor(s, off);
        ss += __shfl_xor(ss, off);
    }
    float mean = s * (1.f / C_);
    float var  = ss * (1.f / C_) - mean * mean;
    float rstd = rsqrtf(var + EPS_);
    float2 g  = *(const float2*)&gamma[lane * 2];
    float2 bt = *(const float2*)&beta[lane * 2];
    float2 o;
    o.x = (v.x - mean) * rstd * g.x + bt.x;
    o.y = (v.y - mean) * rstd * g.y + bt.y;
    *(float2*)&out[(size_t)m * C_ + lane * 2] = o;
}

// ---------------------------------------------------------------------------
// Fused window attention: one 256-thread block per window; wave h = head h.
// K,V staged in LDS (broadcast reads in the dot loops); softmax in registers.
// qkv layout: row m = w*64+i, 384 cols = [q(0:128) | k(128:256) | v(256:384)].
// qkv/aout are chunk-local; w_off gives the global window id for the mask.
// ---------------------------------------------------------------------------
__global__ __launch_bounds__(256)
void attn_kernel(const float* __restrict__ qkv, const float* __restrict__ mask,
                 const float* __restrict__ relb, float* __restrict__ aout,
                 int w_off)
{
    int w = blockIdx.x;              // local window
    int h = threadIdx.x >> 6;        // head
    int i = threadIdx.x & 63;        // query row / lane
    __shared__ float kls[H_][WS_][HD_];
    __shared__ float vls[H_][WS_][HD_];

    const float* base = qkv + (size_t)w * WS_ * 384;
#pragma unroll
    for (int it = 0; it < 8; ++it) {
        int f  = it * 64 + i;        // float4 index, 512 per matrix
        int r  = f >> 3;
        int d4 = (f & 7) << 2;
        *(float4*)&kls[h][r][d4] = *(const float4*)&base[r * 384 + C_     + h * HD_ + d4];
        *(float4*)&vls[h][r][d4] = *(const float4*)&base[r * 384 + 2 * C_ + h * HD_ + d4];
    }
    float q[HD_];
#pragma unroll
    for (int d4 = 0; d4 < HD_; d4 += 4) {
        float4 t = *(const float4*)&base[i * 384 + h * HD_ + d4];
        q[d4 + 0] = t.x * SCALE_; q[d4 + 1] = t.y * SCALE_;
        q[d4 + 2] = t.z * SCALE_; q[d4 + 3] = t.w * SCALE_;
    }
    __syncthreads();

    float s[WS_];
#pragma unroll
    for (int j = 0; j < WS_; ++j) {
        float acc = 0.f;
#pragma unroll
        for (int d4 = 0; d4 < HD_; d4 += 4) {
            float4 kf = *(const float4*)&kls[h][j][d4];   // broadcast read
            acc += q[d4+0]*kf.x + q[d4+1]*kf.y + q[d4+2]*kf.z + q[d4+3]*kf.w;
        }
        s[j] = acc;
    }
    int wn = (w_off + w) & (NW_ - 1);
    const float* mrow = mask + ((size_t)wn * WS_ + i) * WS_;
    float mx = -1e30f;
#pragma unroll
    for (int j = 0; j < WS_; ++j) {
        s[j] += relb[(i - j + WS_ - 1) * H_ + h] + mrow[j];
        mx = fmaxf(mx, s[j]);
    }
    float sum = 0.f;
#pragma unroll
    for (int j = 0; j < WS_; ++j) { s[j] = __expf(s[j] - mx); sum += s[j]; }
    float inv = 1.f / sum;

    float o[HD_] = {};
#pragma unroll
    for (int j = 0; j < WS_; ++j) {
        float p = s[j];
#pragma unroll
        for (int d4 = 0; d4 < HD_; d4 += 4) {
            float4 vf = *(const float4*)&vls[h][j][d4];   // broadcast read
            o[d4+0] += p * vf.x; o[d4+1] += p * vf.y;
            o[d4+2] += p * vf.z; o[d4+3] += p * vf.w;
        }
    }
    float* orow = aout + ((size_t)(w * WS_ + i)) * C_ + h * HD_;
#pragma unroll
    for (int d4 = 0; d4 < HD_; d4 += 4) {
        float4 t;
        t.x = o[d4+0]*inv; t.y = o[d4+1]*inv; t.z = o[d4+2]*inv; t.w = o[d4+3]*inv;
        *(float4*)&orow[d4] = t;
    }
}

// ---------------------------------------------------------------------------
// fp32 GEMM: C[M,N] = A[M,K] @ B[K,N] + bias, tile 128x128, BK=32, dbuf LDS,
// 256 threads, 8x8 micro-tile. A/B are chunk-local. EPI:
//   0 = store local
//   1 = reverse-roll + x residual, GLOBAL rows (m_off): writes x1 into d_out
//   2 = exact GELU, store local
//   3 = accumulate into Cd at GLOBAL rows (d_out += y)
// ---------------------------------------------------------------------------
#define BM 128
#define BN 128
#define BK 32

template<int EPI>
__global__ __launch_bounds__(256, 2)
void gemm_k(const float* __restrict__ A, const float* __restrict__ Bm,
            const float* __restrict__ bias, float* __restrict__ Cd,
            const float* __restrict__ X, int M, int N, int K, int m_off)
{
    __shared__ float As[2][BK][132];   // [k][m], padded stride
    __shared__ float Bs[2][BK][BN];    // [k][n]
    const int t  = threadIdx.x;
    const int m0 = blockIdx.x * BM;
    const int n0 = blockIdx.y * BN;
    const int tx = t & 15, ty = t >> 4;

    float4 aReg[4], bReg[4];

    auto loadA = [&](int kc) {
#pragma unroll
        for (int it = 0; it < 4; ++it) {
            int idx = it * 256 + t;
            int r = idx >> 3, kq = (idx & 7) << 2;
            aReg[it] = *(const float4*)&A[(size_t)(m0 + r) * K + kc + kq];
        }
    };
    auto loadB = [&](int kc) {
#pragma unroll
        for (int it = 0; it < 4; ++it) {
            int idx = it * 256 + t;
            int kr = idx >> 5, nq = (idx & 31) << 2;
            bReg[it] = *(const float4*)&Bm[(size_t)(kc + kr) * N + n0 + nq];
        }
    };
    auto storeT = [&](int buf) {
#pragma unroll
        for (int it = 0; it < 4; ++it) {
            int idx = it * 256 + t;
            int r = idx >> 3, kq = (idx & 7) << 2;
            As[buf][kq + 0][r] = aReg[it].x;
            As[buf][kq + 1][r] = aReg[it].y;
            As[buf][kq + 2][r] = aReg[it].z;
            As[buf][kq + 3][r] = aReg[it].w;
            int kr = idx >> 5, nq = (idx & 31) << 2;
            *(float4*)&Bs[buf][kr][nq] = bReg[it];
        }
    };

    float acc[8][8] = {};
    loadA(0); loadB(0);
    storeT(0);
    __syncthreads();

    const int nChunk = K / BK;
    for (int c = 0; c < nChunk; ++c) {
        if (c + 1 < nChunk) { loadA((c + 1) * BK); loadB((c + 1) * BK); }
        const int cur = c & 1;
#pragma unroll
        for (int k = 0; k < BK; ++k) {
            float a[8], b[8];
            *(float4*)&a[0] = *(const float4*)&As[cur][k][ty * 8];
            *(float4*)&a[4] = *(const float4*)&As[cur][k][ty * 8 + 4];
            *(float4*)&b[0] = *(const float4*)&Bs[cur][k][tx * 8];
            *(float4*)&b[4] = *(const float4*)&Bs[cur][k][tx * 8 + 4];
#pragma unroll
            for (int i = 0; i < 8; ++i)
#pragma unroll
                for (int j = 0; j < 8; ++j)
                    acc[i][j] += a[i] * b[j];
        }
        if (c + 1 < nChunk) {
            storeT((c + 1) & 1);
            __syncthreads();
        }
    }

    float bv[8];
    *(float4*)&bv[0] = *(const float4*)&bias[n0 + tx * 8];
    *(float4*)&bv[4] = *(const float4*)&bias[n0 + tx * 8 + 4];

#pragma unroll
    for (int ii = 0; ii < 8; ++ii) {
        int mrow = m0 + ty * 8 + ii;          // local row
        float vout[8];
#pragma unroll
        for (int j = 0; j < 8; ++j) vout[j] = acc[ii][j] + bv[j];

        if (EPI == 0) {
            float* cr = Cd + (size_t)mrow * N + n0 + tx * 8;
            *(float4*)&cr[0] = *(float4*)&vout[0];
            *(float4*)&cr[4] = *(float4*)&vout[4];
        } else if (EPI == 1) {
            int gr = m_off + mrow;
            int b = gr >> 14, l = gr & (L_ - 1);
            size_t dst = ((size_t)((b << 14) | ((l + SHIFT_) & (L_ - 1)))) * C_ + tx * 8;
            float4 x0 = *(const float4*)&X[dst];
            float4 x1 = *(const float4*)&X[dst + 4];
            float4 o0, o1;
            o0.x = vout[0] + x0.x; o0.y = vout[1] + x0.y;
            o0.z = vout[2] + x0.z; o0.w = vout[3] + x0.w;
            o1.x = vout[4] + x1.x; o1.y = vout[5] + x1.y;
            o1.z = vout[6] + x1.z; o1.w = vout[7] + x1.w;
            *(float4*)&Cd[dst]     = o0;
            *(float4*)&Cd[dst + 4] = o1;
        } else if (EPI == 2) {
#pragma unroll
            for (int j = 0; j < 8; ++j) {
                float v = vout[j];
                vout[j] = 0.5f * v * (1.f + erff(v * 0.70710678118654752f));
            }
            float* cr = Cd + (size_t)mrow * N + n0 + tx * 8;
            *(float4*)&cr[0] = *(float4*)&vout[0];
            *(float4*)&cr[4] = *(float4*)&vout[4];
        } else {  // EPI == 3: accumulate into Cd at global rows
            float* cr = Cd + (size_t)(m_off + mrow) * C_ + tx * 8;
            float4 c0 = *(float4*)&cr[0];
            float4 c1 = *(float4*)&cr[4];
            c0.x += vout[0]; c0.y += vout[1]; c0.z += vout[2]; c0.w += vout[3];
            c1.x += vout[4]; c1.y += vout[5]; c1.z += vout[6]; c1.w += vout[7];
            *(float4*)&cr[0] = c0;
            *(float4*)&cr[4] = c1;
        }
    }
}

// ---------------------------------------------------------------------------
extern "C" void kernel_launch(void* const* d_in, const int* in_sizes, int n_in,
                              void* d_out, int out_size, void* d_ws, size_t ws_size,
                              hipStream_t stream)
{
    const float* x      = (const float*)d_in[0];
    const float* mask   = (const float*)d_in[1];
    const float* gamma1 = (const float*)d_in[2];
    const float* beta1  = (const float*)d_in[3];
    const float* w_qkv  = (const float*)d_in[4];
    const float* b_qkv  = (const float*)d_in[5];
    const float* relb   = (const float*)d_in[6];
    const float* w_proj = (const float*)d_in[7];
    const float* b_proj = (const float*)d_in[8];
    const float* gamma2 = (const float*)d_in[9];
    const float* beta2  = (const float*)d_in[10];
    const float* w_fc1  = (const float*)d_in[11];
    const float* b_fc1  = (const float*)d_in[12];
    const float* w_fc2  = (const float*)d_in[13];
    const float* b_fc2  = (const float*)d_in[14];
    float* out = (float*)d_out;
    float* ws  = (float*)d_ws;

    // Chunk over whole batches so the cyclic roll stays inside a chunk.
    // ws requirement per chunk: Mc*(C + HID) floats.
    size_t wsFloats = ws_size / sizeof(float);
    int nch;
    if      (wsFloats >= (size_t)M_ * 640)      nch = 1;   // 336 MB
    else if (wsFloats >= (size_t)(M_/2) * 640)  nch = 2;   // 168 MB
    else if (wsFloats >= (size_t)(M_/4) * 640)  nch = 4;   //  84 MB
    else                                        nch = 8;   //  42 MB
    const int Mc = M_ / nch;

    float* buf0 = ws;                       // h / attn_out / m2 : Mc x 128
    float* buf1 = ws + (size_t)Mc * C_;     // qkv (Mc x 384) / g (Mc x 512)

    for (int ch = 0; ch < nch; ++ch) {
        int m0 = ch * Mc;

        // 1. LN1 + cyclic shift (-SHIFT)
        ln_kernel<<<dim3(Mc / 4), dim3(256), 0, stream>>>(
            x, buf0, gamma1, beta1, 1, m0);

        // 2. qkv = h @ w_qkv + b_qkv            (Mc x 384)
        gemm_k<0><<<dim3(Mc / BM, 3), dim3(256), 0, stream>>>(
            buf0, w_qkv, b_qkv, buf1, nullptr, Mc, 3 * C_, C_, 0);

        // 3. window attention -> attn_out (Mc x 128)
        attn_kernel<<<dim3(Mc / WS_), dim3(256), 0, stream>>>(
            buf1, mask, relb, buf0, m0 / WS_);

        // 4. proj + reverse shift + residual -> d_out rows for these batches
        gemm_k<1><<<dim3(Mc / BM, 1), dim3(256), 0, stream>>>(
            buf0, w_proj, b_proj, out, x, Mc, C_, C_, m0);

        // 5. m2 = LN2(x1)   (x1 rows for this chunk are complete: roll is batch-local)
        ln_kernel<<<dim3(Mc / 4), dim3(256), 0, stream>>>(
            out, buf0, gamma2, beta2, 0, m0);

        // 6. g = gelu(m2 @ w_fc1 + b_fc1)       (Mc x 512)
        gemm_k<2><<<dim3(Mc / BM, HID_ / BN), dim3(256), 0, stream>>>(
            buf0, w_fc1, b_fc1, buf1, nullptr, Mc, HID_, C_, 0);

        // 7. d_out += g @ w_fc2 + b_fc2
        gemm_k<3><<<dim3(Mc / BM, 1), dim3(256), 0, stream>>>(
            buf1, w_fc2, b_fc2, out, nullptr, Mc, C_, HID_, m0);
    }
}

// Round 3
// 708.133 us; speedup vs baseline: 12.9175x; 12.9175x over previous
//
#include <hip/hip_runtime.h>
#include <math.h>

#define B_ 8
#define L_ 16384
#define C_ 128
#define H_ 4
#define WS_ 64
#define SHIFT_ 32
#define NW_ 256
#define HD_ 32
#define HID_ 512
#define M_ (B_*L_)
#define SCALE_ 0.17677669529663687f
#define EPS_ 1e-5f

using short8 = __attribute__((ext_vector_type(8))) short;
using f32x4  = __attribute__((ext_vector_type(4))) float;
using gas1   = const __attribute__((address_space(1))) unsigned int*;
using las3   = __attribute__((address_space(3))) unsigned int*;

// split v ~= hi + lo, both bf16 (hi truncated, lo rounds the remainder)
__device__ __forceinline__ void bsplit(float v, unsigned short& h, unsigned short& l)
{
    unsigned b = __float_as_uint(v);
    h = (unsigned short)(b >> 16);
    float vh = __uint_as_float(b & 0xffff0000u);
    float lo = v - vh;
    l = (unsigned short)(__float_as_uint(lo) >> 16);
}

// ---------------------------------------------------------------------------
// LayerNorm -> tiled-split-bf16 output. Tiled layout for A[M][K=128]:
// elem (m,k) at ((m>>4)*16 + (k>>3))*128 + (m&15)*8 + (k&7).
// One wave per row, 4 rows / block. Reads global rows (m_off+, opt. shifted).
// ---------------------------------------------------------------------------
__global__ __launch_bounds__(256)
void ln_ts(const float* __restrict__ in, unsigned short* __restrict__ oh,
           unsigned short* __restrict__ ol,
           const float* __restrict__ gamma, const float* __restrict__ beta,
           int do_shift, int m_off)
{
    int m    = blockIdx.x * 4 + (threadIdx.x >> 6);   // local row
    int lane = threadIdx.x & 63;
    int gr   = m_off + m;
    int src  = gr;
    if (do_shift) {
        int b = gr >> 14, l = gr & (L_ - 1);
        src = (b << 14) | ((l + SHIFT_) & (L_ - 1));
    }
    const float* row = in + (size_t)src * C_;
    float2 v = *(const float2*)&row[lane * 2];
    float s  = v.x + v.y;
    float ss = v.x * v.x + v.y * v.y;
#pragma unroll
    for (int off = 1; off < 64; off <<= 1) {
        s  += __shfl_xor(s, off);
        ss += __shfl_xor(ss, off);
    }
    float mean = s * (1.f / C_);
    float var  = ss * (1.f / C_) - mean * mean;
    float rstd = rsqrtf(var + EPS_);
    float2 g  = *(const float2*)&gamma[lane * 2];
    float2 bt = *(const float2*)&beta[lane * 2];
    float ox = (v.x - mean) * rstd * g.x + bt.x;
    float oy = (v.y - mean) * rstd * g.y + bt.y;
    int k = lane * 2;
    unsigned idx = (unsigned)((m >> 4) * 16 + (k >> 3)) * 128 + (m & 15) * 8 + (k & 7);
    unsigned short h0, l0, h1, l1;
    bsplit(ox, h0, l0); bsplit(oy, h1, l1);
    *(unsigned*)&oh[idx] = (unsigned)h0 | ((unsigned)h1 << 16);
    *(unsigned*)&ol[idx] = (unsigned)l0 | ((unsigned)l1 << 16);
}

// ---------------------------------------------------------------------------
// Weight convert: W[K][N] f32 -> tiled-split bf16 of W^T:
// (k,n) -> base + ((n>>4)*(K>>3) + (k>>3))*128 + (n&15)*8 + (k&7).
// Concatenated: qkv[0,49152) proj[49152,65536) fc1[65536,131072) fc2[131072,196608)
// ---------------------------------------------------------------------------
__global__ __launch_bounds__(256)
void wconv(const float* __restrict__ wq, const float* __restrict__ wp,
           const float* __restrict__ w1, const float* __restrict__ w2,
           unsigned short* __restrict__ th, unsigned short* __restrict__ tl)
{
    int e = blockIdx.x * 256 + threadIdx.x;
    const float* W; int K, N, base, local;
    if (e < 49152)       { W = wq; K = 128; N = 384; base = 0;      local = e; }
    else if (e < 65536)  { W = wp; K = 128; N = 128; base = 49152;  local = e - 49152; }
    else if (e < 131072) { W = w1; K = 128; N = 512; base = 65536;  local = e - 65536; }
    else                 { W = w2; K = 512; N = 128; base = 131072; local = e - 131072; }
    int n = local / K, k = local % K;
    float v = W[(size_t)k * N + n];
    unsigned short h, l; bsplit(v, h, l);
    int idx = base + ((n >> 4) * (K >> 3) + (k >> 3)) * 128 + (n & 15) * 8 + (k & 7);
    th[idx] = h; tl[idx] = l;
}

// ---------------------------------------------------------------------------
// Fused window attention (fp32 math, unchanged) -> tiled-split bf16 output.
// ---------------------------------------------------------------------------
__global__ __launch_bounds__(256)
void attn_kernel(const float* __restrict__ qkv, const float* __restrict__ mask,
                 const float* __restrict__ relb,
                 unsigned short* __restrict__ Oh, unsigned short* __restrict__ Ol,
                 int w_off)
{
    int w = blockIdx.x;
    int h = threadIdx.x >> 6;
    int i = threadIdx.x & 63;
    __shared__ float kls[H_][WS_][HD_];
    __shared__ float vls[H_][WS_][HD_];

    const float* base = qkv + (size_t)w * WS_ * 384;
#pragma unroll
    for (int it = 0; it < 8; ++it) {
        int f  = it * 64 + i;
        int r  = f >> 3;
        int d4 = (f & 7) << 2;
        *(float4*)&kls[h][r][d4] = *(const float4*)&base[r * 384 + C_     + h * HD_ + d4];
        *(float4*)&vls[h][r][d4] = *(const float4*)&base[r * 384 + 2 * C_ + h * HD_ + d4];
    }
    float q[HD_];
#pragma unroll
    for (int d4 = 0; d4 < HD_; d4 += 4) {
        float4 t = *(const float4*)&base[i * 384 + h * HD_ + d4];
        q[d4 + 0] = t.x * SCALE_; q[d4 + 1] = t.y * SCALE_;
        q[d4 + 2] = t.z * SCALE_; q[d4 + 3] = t.w * SCALE_;
    }
    __syncthreads();

    float s[WS_];
#pragma unroll
    for (int j = 0; j < WS_; ++j) {
        float acc = 0.f;
#pragma unroll
        for (int d4 = 0; d4 < HD_; d4 += 4) {
            float4 kf = *(const float4*)&kls[h][j][d4];
            acc += q[d4+0]*kf.x + q[d4+1]*kf.y + q[d4+2]*kf.z + q[d4+3]*kf.w;
        }
        s[j] = acc;
    }
    int wn = (w_off + w) & (NW_ - 1);
    const float* mrow = mask + ((size_t)wn * WS_ + i) * WS_;
    float mx = -1e30f;
#pragma unroll
    for (int j = 0; j < WS_; ++j) {
        s[j] += relb[(i - j + WS_ - 1) * H_ + h] + mrow[j];
        mx = fmaxf(mx, s[j]);
    }
    float sum = 0.f;
#pragma unroll
    for (int j = 0; j < WS_; ++j) { s[j] = __expf(s[j] - mx); sum += s[j]; }
    float inv = 1.f / sum;

    float o[HD_] = {};
#pragma unroll
    for (int j = 0; j < WS_; ++j) {
        float p = s[j];
#pragma unroll
        for (int d4 = 0; d4 < HD_; d4 += 4) {
            float4 vf = *(const float4*)&vls[h][j][d4];
            o[d4+0] += p * vf.x; o[d4+1] += p * vf.y;
            o[d4+2] += p * vf.z; o[d4+3] += p * vf.w;
        }
    }
    // write tiled-split: row gm = w*64+i, cols h*32 .. h*32+31 (K=128 tiling)
    int gm = w * WS_ + i;
    unsigned pb = (unsigned)(gm >> 4) * 16;
    unsigned rb = (unsigned)(gm & 15) * 8;
#pragma unroll
    for (int oc = 0; oc < 4; ++oc) {
        unsigned short hh[8], ll[8];
#pragma unroll
        for (int sN = 0; sN < 8; ++sN) bsplit(o[oc * 8 + sN] * inv, hh[sN], ll[sN]);
        unsigned idx = (pb + (h * 4 + oc)) * 128 + rb;
        uint4 ph, pl;
        ph.x = hh[0] | (hh[1] << 16); ph.y = hh[2] | (hh[3] << 16);
        ph.z = hh[4] | (hh[5] << 16); ph.w = hh[6] | (hh[7] << 16);
        pl.x = ll[0] | (ll[1] << 16); pl.y = ll[2] | (ll[3] << 16);
        pl.z = ll[4] | (ll[5] << 16); pl.w = ll[6] | (ll[7] << 16);
        *(uint4*)&Oh[idx] = ph;
        *(uint4*)&Ol[idx] = pl;
    }
}

// ---------------------------------------------------------------------------
// MFMA split-bf16 GEMM: C[M,N] = A[M,K]@B[K,N] + bias.
// A,B in tiled-split layout (panel stride 16*K). Tile 128x128, BK=32, dbuf,
// 4 waves (2x2), each wave 64x64 via 4x4 fragments of 16x16x32 MFMA, 3-term.
// EPI: 0=f32 row-major store; 1=reverse-roll + X residual (global rows);
//      2=exact GELU -> tiled-split store (Gh/Gl, next-K = N);
//      3=accumulate into Cd at global rows.
// ---------------------------------------------------------------------------
#define GLDS(GP, LP) __builtin_amdgcn_global_load_lds((gas1)(const void*)(GP), \
                                                      (las3)(void*)(LP), 16, 0, 0)

template<int EPI>
__global__ __launch_bounds__(256, 2)
void mgemm(const unsigned short* __restrict__ Ahi, const unsigned short* __restrict__ Alo,
           const unsigned short* __restrict__ Bhi, const unsigned short* __restrict__ Blo,
           const float* __restrict__ bias, float* __restrict__ Cd,
           unsigned short* __restrict__ Gh, unsigned short* __restrict__ Gl,
           const float* __restrict__ X, int M, int N, int K, int m_off)
{
    __shared__ unsigned short lds[2][4][4096];   // [buf][Ahi,Alo,Bhi,Blo][8KB]
    const int t    = threadIdx.x;
    const int lane = t & 63, wid = t >> 6;
    const int wmP  = (wid >> 1) * 4;             // A-panel base within tile
    const int wnP  = (wid & 1) * 4;              // B-panel base within tile
    const int pm0  = blockIdx.x * 8;
    const int pn0  = blockIdx.y * 8;
    const int lro  = (lane >> 4) * 128 + (lane & 15) * 8;
    const size_t pstr = (size_t)16 * K;

    f32x4 acc[4][4] = {};

#define STAGE(buf, kc) { \
    const size_t ko = (size_t)((kc) >> 3) * 128; \
    _Pragma("unroll") \
    for (int sh = 0; sh < 2; ++sh) { \
        const int f = sh * 2048 + t * 8; \
        const int p = f >> 9, o = f & 511; \
        const size_t ga = (size_t)(pm0 + p) * pstr + ko + o; \
        const size_t gb = (size_t)(pn0 + p) * pstr + ko + o; \
        GLDS(Ahi + ga, &lds[buf][0][f]); \
        GLDS(Alo + ga, &lds[buf][1][f]); \
        GLDS(Bhi + gb, &lds[buf][2][f]); \
        GLDS(Blo + gb, &lds[buf][3][f]); \
    } }

#define COMPUTE(buf) { \
    short8 ah[4], al[4], bh[4], bl[4]; \
    _Pragma("unroll") for (int i = 0; i < 4; ++i) { \
        ah[i] = *(const short8*)&lds[buf][0][(wmP + i) * 512 + lro]; \
        al[i] = *(const short8*)&lds[buf][1][(wmP + i) * 512 + lro]; \
        bh[i] = *(const short8*)&lds[buf][2][(wnP + i) * 512 + lro]; \
        bl[i] = *(const short8*)&lds[buf][3][(wnP + i) * 512 + lro]; \
    } \
    _Pragma("unroll") for (int i = 0; i < 4; ++i) \
    _Pragma("unroll") for (int j = 0; j < 4; ++j) { \
        acc[i][j] = __builtin_amdgcn_mfma_f32_16x16x32_bf16(ah[i], bh[j], acc[i][j], 0, 0, 0); \
        acc[i][j] = __builtin_amdgcn_mfma_f32_16x16x32_bf16(ah[i], bl[j], acc[i][j], 0, 0, 0); \
        acc[i][j] = __builtin_amdgcn_mfma_f32_16x16x32_bf16(al[i], bh[j], acc[i][j], 0, 0, 0); \
    } }

    const int nst = K >> 5;
    STAGE(0, 0);
    __syncthreads();
    int cur = 0;
    for (int c = 0; c < nst; ++c) {
        if (c + 1 < nst) STAGE(cur ^ 1, (c + 1) << 5);
        COMPUTE(cur);
        __syncthreads();
        cur ^= 1;
    }
#undef STAGE
#undef COMPUTE

    const int m0r = blockIdx.x * 128;
    const int n0  = blockIdx.y * 128;
#pragma unroll
    for (int j = 0; j < 4; ++j) {
        const int col = n0 + (wid & 1) * 64 + j * 16 + (lane & 15);
        const float bv = bias[col];
#pragma unroll
        for (int i = 0; i < 4; ++i) {
#pragma unroll
            for (int r = 0; r < 4; ++r) {
                const int row = m0r + (wid >> 1) * 64 + i * 16 + (lane >> 4) * 4 + r;
                float v = acc[i][j][r] + bv;
                if (EPI == 0) {
                    Cd[(size_t)row * N + col] = v;
                } else if (EPI == 1) {
                    int gr = m_off + row;
                    int b = gr >> 14, l = gr & (L_ - 1);
                    size_t dst = ((size_t)((b << 14) | ((l + SHIFT_) & (L_ - 1)))) * C_ + col;
                    Cd[dst] = v + X[dst];
                } else if (EPI == 2) {
                    v = 0.5f * v * (1.f + erff(v * 0.70710678118654752f));
                    unsigned short hh, llv; bsplit(v, hh, llv);
                    size_t idx = ((size_t)(row >> 4) * (N >> 3) + (col >> 3)) * 128
                               + (row & 15) * 8 + (col & 7);
                    Gh[idx] = hh; Gl[idx] = llv;
                } else {
                    size_t di = (size_t)(m_off + row) * C_ + col;
                    Cd[di] += v;
                }
            }
        }
    }
}

// ---------------------------------------------------------------------------
extern "C" void kernel_launch(void* const* d_in, const int* in_sizes, int n_in,
                              void* d_out, int out_size, void* d_ws, size_t ws_size,
                              hipStream_t stream)
{
    const float* x      = (const float*)d_in[0];
    const float* mask   = (const float*)d_in[1];
    const float* gamma1 = (const float*)d_in[2];
    const float* beta1  = (const float*)d_in[3];
    const float* w_qkv  = (const float*)d_in[4];
    const float* b_qkv  = (const float*)d_in[5];
    const float* relb   = (const float*)d_in[6];
    const float* w_proj = (const float*)d_in[7];
    const float* b_proj = (const float*)d_in[8];
    const float* gamma2 = (const float*)d_in[9];
    const float* beta2  = (const float*)d_in[10];
    const float* w_fc1  = (const float*)d_in[11];
    const float* b_fc1  = (const float*)d_in[12];
    const float* w_fc2  = (const float*)d_in[13];
    const float* b_fc2  = (const float*)d_in[14];
    float* out = (float*)d_out;

    // pick chunk count: need = 786432 (weights) + Mc*3072 bytes
    int nch = 8;
    for (int c = 1; c <= 8; c <<= 1) {
        size_t need = 786432 + (size_t)(M_ / c) * 3072;
        if (need <= ws_size) { nch = c; break; }
    }
    const int Mc = M_ / nch;

    char* basep = (char*)d_ws;
    unsigned short* wth = (unsigned short*)basep;        // 196608 ushort
    unsigned short* wtl = wth + 196608;
    char* dyn = basep + 786432;
    unsigned short* h_hi = (unsigned short*)dyn;         // Mc x 128 (h / m2)
    unsigned short* h_lo = h_hi + (size_t)Mc * C_;
    unsigned short* a_hi = (unsigned short*)(dyn + (size_t)Mc * 512);
    unsigned short* a_lo = a_hi + (size_t)Mc * C_;
    char* big = dyn + (size_t)Mc * 1024;
    float*          qkvb = (float*)big;                  // Mc x 384 f32
    unsigned short* g_hi = (unsigned short*)big;         // Mc x 512 split
    unsigned short* g_lo = g_hi + (size_t)Mc * HID_;

    // weights -> tiled-split (once per launch)
    wconv<<<dim3(768), dim3(256), 0, stream>>>(w_qkv, w_proj, w_fc1, w_fc2, wth, wtl);

    for (int ch = 0; ch < nch; ++ch) {
        int m0 = ch * Mc;

        // 1. LN1 + cyclic shift -> h (tiled-split)
        ln_ts<<<dim3(Mc / 4), dim3(256), 0, stream>>>(x, h_hi, h_lo, gamma1, beta1, 1, m0);

        // 2. qkv = h @ w_qkv + b_qkv  (f32 row-major for attention)
        mgemm<0><<<dim3(Mc / 128, 3), dim3(256), 0, stream>>>(
            h_hi, h_lo, wth, wtl, b_qkv, qkvb, nullptr, nullptr, nullptr,
            Mc, 3 * C_, C_, 0);

        // 3. window attention -> a (tiled-split)
        attn_kernel<<<dim3(Mc / WS_), dim3(256), 0, stream>>>(
            qkvb, mask, relb, a_hi, a_lo, m0 / WS_);

        // 4. proj + reverse roll + residual -> d_out holds x1
        mgemm<1><<<dim3(Mc / 128, 1), dim3(256), 0, stream>>>(
            a_hi, a_lo, wth + 49152, wtl + 49152, b_proj, out, nullptr, nullptr, x,
            Mc, C_, C_, m0);

        // 5. m2 = LN2(x1) -> h (tiled-split, reuse)
        ln_ts<<<dim3(Mc / 4), dim3(256), 0, stream>>>(out, h_hi, h_lo, gamma2, beta2, 0, m0);

        // 6. g = gelu(m2 @ w_fc1 + b_fc1) -> tiled-split (K_next = 512)
        mgemm<2><<<dim3(Mc / 128, HID_ / 128), dim3(256), 0, stream>>>(
            h_hi, h_lo, wth + 65536, wtl + 65536, b_fc1, nullptr, g_hi, g_lo, nullptr,
            Mc, HID_, C_, 0);

        // 7. d_out += g @ w_fc2 + b_fc2
        mgemm<3><<<dim3(Mc / 128, 1), dim3(256), 0, stream>>>(
            g_hi, g_lo, wth + 131072, wtl + 131072, b_fc2, out, nullptr, nullptr, nullptr,
            Mc, C_, HID_, m0);
    }
}

// Round 5
// 635.846 us; speedup vs baseline: 14.3860x; 1.1137x over previous
//
#include <hip/hip_runtime.h>
#include <math.h>

#define B_ 8
#define L_ 16384
#define C_ 128
#define H_ 4
#define WS_ 64
#define SHIFT_ 32
#define NW_ 256
#define HD_ 32
#define HID_ 512
#define M_ (B_*L_)
#define SCALE_ 0.17677669529663687f
#define EPS_ 1e-5f

using short8 = __attribute__((ext_vector_type(8))) short;
using f32x4  = __attribute__((ext_vector_type(4))) float;
using gas1   = const __attribute__((address_space(1))) unsigned int*;
using las3   = __attribute__((address_space(3))) unsigned int*;
typedef unsigned short ushort_t;

#define GLDS(GP, LP) __builtin_amdgcn_global_load_lds((gas1)(const void*)(GP), \
                                                      (las3)(void*)(LP), 16, 0, 0)

__device__ __forceinline__ f32x4 mfma16(short8 a, short8 b, f32x4 c) {
    return __builtin_amdgcn_mfma_f32_16x16x32_bf16(a, b, c, 0, 0, 0);
}

// RNE float -> bf16
__device__ __forceinline__ ushort_t f2bf(float v)
{
    unsigned u = __float_as_uint(v);
    return (ushort_t)((u + 0x7fff + ((u >> 16) & 1)) >> 16);
}
// split v ~= hi + lo (hi trunc, lo rounds remainder)
__device__ __forceinline__ void bsplit(float v, ushort_t& h, ushort_t& l)
{
    unsigned b = __float_as_uint(v);
    h = (ushort_t)(b >> 16);
    float vh = __uint_as_float(b & 0xffff0000u);
    l = (ushort_t)(__float_as_uint(v - vh) >> 16);
}
__device__ __forceinline__ float bf2f(unsigned s) { return __uint_as_float(s << 16); }

// ---------------------------------------------------------------------------
// LayerNorm -> tiled-split output.  (m,k) -> ((m>>4)*16+(k>>3))*128+(m&15)*8+(k&7)
// ---------------------------------------------------------------------------
__global__ __launch_bounds__(256)
void ln_ts(const float* __restrict__ in, ushort_t* __restrict__ oh,
           ushort_t* __restrict__ ol,
           const float* __restrict__ gamma, const float* __restrict__ beta,
           int do_shift, int m_off)
{
    int m    = blockIdx.x * 4 + (threadIdx.x >> 6);
    int lane = threadIdx.x & 63;
    int gr   = m_off + m;
    int src  = gr;
    if (do_shift) {
        int b = gr >> 14, l = gr & (L_ - 1);
        src = (b << 14) | ((l + SHIFT_) & (L_ - 1));
    }
    const float* row = in + (size_t)src * C_;
    float2 v = *(const float2*)&row[lane * 2];
    float s  = v.x + v.y;
    float ss = v.x * v.x + v.y * v.y;
#pragma unroll
    for (int off = 1; off < 64; off <<= 1) {
        s  += __shfl_xor(s, off);
        ss += __shfl_xor(ss, off);
    }
    float mean = s * (1.f / C_);
    float var  = ss * (1.f / C_) - mean * mean;
    float rstd = rsqrtf(var + EPS_);
    float2 g  = *(const float2*)&gamma[lane * 2];
    float2 bt = *(const float2*)&beta[lane * 2];
    float ox = (v.x - mean) * rstd * g.x + bt.x;
    float oy = (v.y - mean) * rstd * g.y + bt.y;
    int k = lane * 2;
    unsigned idx = (unsigned)((m >> 4) * 16 + (k >> 3)) * 128 + (m & 15) * 8 + (k & 7);
    ushort_t h0, l0, h1, l1;
    bsplit(ox, h0, l0); bsplit(oy, h1, l1);
    *(unsigned*)&oh[idx] = (unsigned)h0 | ((unsigned)h1 << 16);
    *(unsigned*)&ol[idx] = (unsigned)l0 | ((unsigned)l1 << 16);
}

// ---------------------------------------------------------------------------
// Weight convert (hi only, RNE): W[K][N] -> tiled W^T
// qkv[0,49152) proj[49152,65536) fc1[65536,131072) fc2[131072,196608)
// ---------------------------------------------------------------------------
__global__ __launch_bounds__(256)
void wconv(const float* __restrict__ wq, const float* __restrict__ wp,
           const float* __restrict__ w1, const float* __restrict__ w2,
           ushort_t* __restrict__ th)
{
    int e = blockIdx.x * 256 + threadIdx.x;
    const float* W; int K, N, base, local;
    if (e < 49152)       { W = wq; K = 128; N = 384; base = 0;      local = e; }
    else if (e < 65536)  { W = wp; K = 128; N = 128; base = 49152;  local = e - 49152; }
    else if (e < 131072) { W = w1; K = 128; N = 512; base = 65536;  local = e - 65536; }
    else                 { W = w2; K = 512; N = 128; base = 131072; local = e - 131072; }
    int n = local / K, k = local % K;
    int idx = base + ((n >> 4) * (K >> 3) + (k >> 3)) * 128 + (n & 15) * 8 + (k & 7);
    th[idx] = f2bf(W[(size_t)k * N + n]);
}

// ---------------------------------------------------------------------------
// Fused window attention. qkv input is bf16 row-major (row m, 384 cols).
// fp32 math; output tiled-split.
// ---------------------------------------------------------------------------
__global__ __launch_bounds__(256)
void attn_kernel(const ushort_t* __restrict__ qkv, const float* __restrict__ mask,
                 const float* __restrict__ relb,
                 ushort_t* __restrict__ Oh, ushort_t* __restrict__ Ol,
                 int w_off)
{
    int w = blockIdx.x;
    int h = threadIdx.x >> 6;
    int i = threadIdx.x & 63;
    __shared__ float kls[H_][WS_][HD_];
    __shared__ float vls[H_][WS_][HD_];

    const ushort_t* base = qkv + (size_t)w * WS_ * 384;
#pragma unroll
    for (int it = 0; it < 8; ++it) {
        int f  = it * 64 + i;          // 512 float4-slots per matrix
        int r  = f >> 3;
        int d4 = (f & 7) << 2;
        uint2 uk = *(const uint2*)&base[r * 384 + C_     + h * HD_ + d4];
        uint2 uv = *(const uint2*)&base[r * 384 + 2 * C_ + h * HD_ + d4];
        float4 kf, vf;
        kf.x = bf2f(uk.x & 0xffff); kf.y = bf2f(uk.x >> 16);
        kf.z = bf2f(uk.y & 0xffff); kf.w = bf2f(uk.y >> 16);
        vf.x = bf2f(uv.x & 0xffff); vf.y = bf2f(uv.x >> 16);
        vf.z = bf2f(uv.y & 0xffff); vf.w = bf2f(uv.y >> 16);
        *(float4*)&kls[h][r][d4] = kf;
        *(float4*)&vls[h][r][d4] = vf;
    }
    float q[HD_];
#pragma unroll
    for (int d4 = 0; d4 < HD_; d4 += 4) {
        uint2 uq = *(const uint2*)&base[i * 384 + h * HD_ + d4];
        q[d4 + 0] = bf2f(uq.x & 0xffff) * SCALE_;
        q[d4 + 1] = bf2f(uq.x >> 16)    * SCALE_;
        q[d4 + 2] = bf2f(uq.y & 0xffff) * SCALE_;
        q[d4 + 3] = bf2f(uq.y >> 16)    * SCALE_;
    }
    __syncthreads();

    float s[WS_];
#pragma unroll
    for (int j = 0; j < WS_; ++j) {
        float acc = 0.f;
#pragma unroll
        for (int d4 = 0; d4 < HD_; d4 += 4) {
            float4 kf = *(const float4*)&kls[h][j][d4];
            acc += q[d4+0]*kf.x + q[d4+1]*kf.y + q[d4+2]*kf.z + q[d4+3]*kf.w;
        }
        s[j] = acc;
    }
    int wn = (w_off + w) & (NW_ - 1);
    const float* mrow = mask + ((size_t)wn * WS_ + i) * WS_;
    float mx = -1e30f;
#pragma unroll
    for (int j = 0; j < WS_; ++j) {
        s[j] += relb[(i - j + WS_ - 1) * H_ + h] + mrow[j];
        mx = fmaxf(mx, s[j]);
    }
    float sum = 0.f;
#pragma unroll
    for (int j = 0; j < WS_; ++j) { s[j] = __expf(s[j] - mx); sum += s[j]; }
    float inv = 1.f / sum;

    float o[HD_] = {};
#pragma unroll
    for (int j = 0; j < WS_; ++j) {
        float p = s[j];
#pragma unroll
        for (int d4 = 0; d4 < HD_; d4 += 4) {
            float4 vf = *(const float4*)&vls[h][j][d4];
            o[d4+0] += p * vf.x; o[d4+1] += p * vf.y;
            o[d4+2] += p * vf.z; o[d4+3] += p * vf.w;
        }
    }
    int gm = w * WS_ + i;
    unsigned pb = (unsigned)(gm >> 4) * 16;
    unsigned rb = (unsigned)(gm & 15) * 8;
#pragma unroll
    for (int oc = 0; oc < 4; ++oc) {
        ushort_t hh[8], ll[8];
#pragma unroll
        for (int sN = 0; sN < 8; ++sN) bsplit(o[oc * 8 + sN] * inv, hh[sN], ll[sN]);
        unsigned idx = (pb + (h * 4 + oc)) * 128 + rb;
        uint4 ph, pl;
        ph.x = hh[0] | (hh[1] << 16); ph.y = hh[2] | (hh[3] << 16);
        ph.z = hh[4] | (hh[5] << 16); ph.w = hh[6] | (hh[7] << 16);
        pl.x = ll[0] | (ll[1] << 16); pl.y = ll[2] | (ll[3] << 16);
        pl.z = ll[4] | (ll[5] << 16); pl.w = ll[6] | (ll[7] << 16);
        *(uint4*)&Oh[idx] = ph;
        *(uint4*)&Ol[idx] = pl;
    }
}

// ---------------------------------------------------------------------------
// MFMA 2-term GEMM (A split hi/lo, B hi). Tile 128x128, BK=32, dbuf.
// EPI: 0 = bf16 row-major store to Cb; 1 = reverse-roll + X residual -> Cd.
// ---------------------------------------------------------------------------
template<int EPI>
__global__ __launch_bounds__(256, 2)
void mgemm(const ushort_t* __restrict__ Ahi, const ushort_t* __restrict__ Alo,
           const ushort_t* __restrict__ Bhi,
           const float* __restrict__ bias, float* __restrict__ Cd,
           ushort_t* __restrict__ Cb, const float* __restrict__ X,
           int M, int N, int K, int m_off)
{
    __shared__ ushort_t lds[2][3][4096];   // Ahi, Alo, Bhi
    const int t    = threadIdx.x;
    const int lane = t & 63, wid = t >> 6;
    const int wmP  = (wid >> 1) * 4;
    const int wnP  = (wid & 1) * 4;
    const int pm0  = blockIdx.x * 8;
    const int pn0  = blockIdx.y * 8;
    const int lro  = (lane >> 4) * 128 + (lane & 15) * 8;
    const size_t pstr = (size_t)16 * K;

    f32x4 acc[4][4] = {};

#define STAGE(buf, kc) { \
    const size_t ko = (size_t)((kc) >> 3) * 128; \
    _Pragma("unroll") \
    for (int sh = 0; sh < 2; ++sh) { \
        const int f = sh * 2048 + t * 8; \
        const int p = f >> 9, o = f & 511; \
        const size_t ga = (size_t)(pm0 + p) * pstr + ko + o; \
        const size_t gb = (size_t)(pn0 + p) * pstr + ko + o; \
        GLDS(Ahi + ga, &lds[buf][0][f]); \
        GLDS(Alo + ga, &lds[buf][1][f]); \
        GLDS(Bhi + gb, &lds[buf][2][f]); \
    } }

#define COMPUTE(buf) { \
    short8 ah[4], al[4], bh[4]; \
    _Pragma("unroll") for (int i = 0; i < 4; ++i) { \
        ah[i] = *(const short8*)&lds[buf][0][(wmP + i) * 512 + lro]; \
        al[i] = *(const short8*)&lds[buf][1][(wmP + i) * 512 + lro]; \
        bh[i] = *(const short8*)&lds[buf][2][(wnP + i) * 512 + lro]; \
    } \
    _Pragma("unroll") for (int i = 0; i < 4; ++i) \
    _Pragma("unroll") for (int j = 0; j < 4; ++j) { \
        acc[i][j] = mfma16(ah[i], bh[j], acc[i][j]); \
        acc[i][j] = mfma16(al[i], bh[j], acc[i][j]); \
    } }

    const int nst = K >> 5;
    STAGE(0, 0);
    __syncthreads();
    int cur = 0;
    for (int c = 0; c < nst; ++c) {
        if (c + 1 < nst) STAGE(cur ^ 1, (c + 1) << 5);
        COMPUTE(cur);
        __syncthreads();
        cur ^= 1;
    }
#undef STAGE
#undef COMPUTE

    const int m0r = blockIdx.x * 128;
    const int n0  = blockIdx.y * 128;
#pragma unroll
    for (int j = 0; j < 4; ++j) {
        const int col = n0 + (wid & 1) * 64 + j * 16 + (lane & 15);
        const float bv = bias[col];
#pragma unroll
        for (int i = 0; i < 4; ++i) {
#pragma unroll
            for (int r = 0; r < 4; ++r) {
                const int row = m0r + (wid >> 1) * 64 + i * 16 + (lane >> 4) * 4 + r;
                float v = acc[i][j][r] + bv;
                if (EPI == 0) {
                    Cb[(size_t)row * N + col] = f2bf(v);
                } else {
                    int gr = m_off + row;
                    int b = gr >> 14, l = gr & (L_ - 1);
                    size_t dst = ((size_t)((b << 14) | ((l + SHIFT_) & (L_ - 1)))) * C_ + col;
                    Cd[dst] = v + X[dst];
                }
            }
        }
    }
}

// ---------------------------------------------------------------------------
// Fused MLP: out += gelu(m2 @ W1 + b1) @ W2 + b2.
// Block = 64 rows, 256 threads (4 waves, 2x2). HID in 4 quarters of 128.
// LDS: A split 32K + g quarter (bf16, tiled) 16K + W dbuf 16K = 64K.
// fc1 2-term, fc2 1-term (g bf16).
// ---------------------------------------------------------------------------
__global__ __launch_bounds__(256, 2)
void mlp_k(const ushort_t* __restrict__ Ahi, const ushort_t* __restrict__ Alo,
           const ushort_t* __restrict__ W1h, const ushort_t* __restrict__ W2h,
           const float* __restrict__ b1, const float* __restrict__ b2,
           float* __restrict__ Out, int m_off)
{
    __shared__ ushort_t Am[2][8192];    // A hi/lo: 4 panels x 2048
    __shared__ ushort_t Gs[8192];       // g quarter tiled: 4 panels x 2048
    __shared__ ushort_t Wl[2][4096];    // weight chunk dbuf
    const int t    = threadIdx.x;
    const int lane = t & 63, wid = t >> 6;
    const int wm   = (wid >> 1) * 32;   // wave row base (0/32)
    const int wnq  = (wid & 1) * 4;     // wave col-block base (x16)
    const int pm0  = blockIdx.x * 4;    // global A panel base

    // stage A (full K=128, contiguous 8192 ushorts from panel pm0)
    {
        const ushort_t* srcH = Ahi + (size_t)pm0 * 2048;
        const ushort_t* srcL = Alo + (size_t)pm0 * 2048;
#pragma unroll
        for (int sh = 0; sh < 4; ++sh) {
            int f = sh * 2048 + t * 8;
            GLDS(srcH + f, &Am[0][f]);
            GLDS(srcL + f, &Am[1][f]);
        }
    }
    auto stageW1 = [&](int buf, int q, int kk) {
#pragma unroll
        for (int sh = 0; sh < 2; ++sh) {
            int f = sh * 2048 + t * 8;
            int p = f >> 9, o = f & 511;
            GLDS(W1h + (size_t)(q * 8 + p) * 2048 + kk * 512 + o, &Wl[buf][f]);
        }
    };
    auto stageW2 = [&](int buf, int q, int kk) {
#pragma unroll
        for (int sh = 0; sh < 2; ++sh) {
            int f = sh * 2048 + t * 8;
            int p = f >> 9, o = f & 511;
            GLDS(W2h + (size_t)p * 8192 + q * 2048 + kk * 512 + o, &Wl[buf][f]);
        }
    };

    f32x4 acc2[2][4] = {};
    stageW1(0, 0, 0);
    __syncthreads();            // A + W1(0,0) ready
    int buf = 0;

    for (int q = 0; q < 4; ++q) {
        f32x4 acc1[2][4] = {};
        // ---- fc1 quarter (K = 128, 4 steps) ----
#pragma unroll
        for (int kk = 0; kk < 4; ++kk) {
            if (kk < 3) stageW1(buf ^ 1, q, kk + 1);
            else        stageW2(buf ^ 1, q, 0);
            short8 bh[4];
#pragma unroll
            for (int j = 0; j < 4; ++j)
                bh[j] = *(const short8*)&Wl[buf][(wnq + j) * 512 + (lane >> 4) * 128 + (lane & 15) * 8];
#pragma unroll
            for (int i = 0; i < 2; ++i) {
                int ai = ((wid >> 1) * 2 + i) * 2048 + (kk * 4 + (lane >> 4)) * 128 + (lane & 15) * 8;
                short8 ah = *(const short8*)&Am[0][ai];
                short8 al = *(const short8*)&Am[1][ai];
#pragma unroll
                for (int j = 0; j < 4; ++j) {
                    acc1[i][j] = mfma16(ah, bh[j], acc1[i][j]);
                    acc1[i][j] = mfma16(al, bh[j], acc1[i][j]);
                }
            }
            __syncthreads();
            buf ^= 1;
        }
        // ---- GELU + write g to LDS (tiled bf16) ----
#pragma unroll
        for (int i = 0; i < 2; ++i)
#pragma unroll
          for (int j = 0; j < 4; ++j) {
            int kg = (wid & 1) * 64 + j * 16 + (lane & 15);
            float bb = b1[q * 128 + kg];
#pragma unroll
            for (int r = 0; r < 4; ++r) {
                int row = wm + i * 16 + (lane >> 4) * 4 + r;
                float v = acc1[i][j][r] + bb;
                v = 0.5f * v * (1.f + erff(v * 0.70710678118654752f));
                Gs[(row >> 4) * 2048 + (kg >> 3) * 128 + (row & 15) * 8 + (kg & 7)] = f2bf(v);
            }
          }
        __syncthreads();        // g visible; W2(q,0) drained by fc1's last barrier
        // ---- fc2 partial (K = 128, 4 steps), 1-term ----
#pragma unroll
        for (int kk = 0; kk < 4; ++kk) {
            if (kk < 3)      stageW2(buf ^ 1, q, kk + 1);
            else if (q < 3)  stageW1(buf ^ 1, q + 1, 0);
            short8 bh[4];
#pragma unroll
            for (int j = 0; j < 4; ++j)
                bh[j] = *(const short8*)&Wl[buf][(wnq + j) * 512 + (lane >> 4) * 128 + (lane & 15) * 8];
#pragma unroll
            for (int i = 0; i < 2; ++i) {
                int gi = ((wid >> 1) * 2 + i) * 2048 + (kk * 4 + (lane >> 4)) * 128 + (lane & 15) * 8;
                short8 ga = *(const short8*)&Gs[gi];
#pragma unroll
                for (int j = 0; j < 4; ++j)
                    acc2[i][j] = mfma16(ga, bh[j], acc2[i][j]);
            }
            __syncthreads();
            buf ^= 1;
        }
    }
    // ---- epilogue: Out += acc2 + b2 ----
#pragma unroll
    for (int i = 0; i < 2; ++i)
#pragma unroll
      for (int j = 0; j < 4; ++j) {
        int col = (wid & 1) * 64 + j * 16 + (lane & 15);
        float bb = b2[col];
#pragma unroll
        for (int r = 0; r < 4; ++r) {
            int row = blockIdx.x * 64 + wm + i * 16 + (lane >> 4) * 4 + r;
            size_t di = (size_t)(m_off + row) * C_ + col;
            Out[di] += acc2[i][j][r] + bb;
        }
      }
}

// ---------------------------------------------------------------------------
extern "C" void kernel_launch(void* const* d_in, const int* in_sizes, int n_in,
                              void* d_out, int out_size, void* d_ws, size_t ws_size,
                              hipStream_t stream)
{
    const float* x      = (const float*)d_in[0];
    const float* mask   = (const float*)d_in[1];
    const float* gamma1 = (const float*)d_in[2];
    const float* beta1  = (const float*)d_in[3];
    const float* w_qkv  = (const float*)d_in[4];
    const float* b_qkv  = (const float*)d_in[5];
    const float* relb   = (const float*)d_in[6];
    const float* w_proj = (const float*)d_in[7];
    const float* b_proj = (const float*)d_in[8];
    const float* gamma2 = (const float*)d_in[9];
    const float* beta2  = (const float*)d_in[10];
    const float* w_fc1  = (const float*)d_in[11];
    const float* b_fc1  = (const float*)d_in[12];
    const float* w_fc2  = (const float*)d_in[13];
    const float* b_fc2  = (const float*)d_in[14];
    float* out = (float*)d_out;

    // ws: weights hi 196608 ushort (384KB) + per-chunk dyn = Mc*1792 bytes
    int nch = 8;
    for (int c = 1; c <= 8; c <<= 1) {
        size_t need = 393216 + (size_t)(M_ / c) * 1792;
        if (need <= ws_size) { nch = c; break; }
    }
    const int Mc = M_ / nch;

    ushort_t* wth  = (ushort_t*)d_ws;
    ushort_t* dynp = wth + 196608;
    ushort_t* h_hi = dynp;                         // Mc x 128 (h / m2)
    ushort_t* h_lo = h_hi + (size_t)Mc * C_;
    ushort_t* a_hi = h_lo + (size_t)Mc * C_;
    ushort_t* a_lo = a_hi + (size_t)Mc * C_;
    ushort_t* qkvb = a_lo + (size_t)Mc * C_;       // Mc x 384 bf16

    wconv<<<dim3(768), dim3(256), 0, stream>>>(w_qkv, w_proj, w_fc1, w_fc2, wth);

    for (int ch = 0; ch < nch; ++ch) {
        int m0 = ch * Mc;

        // 1. LN1 + cyclic shift -> h (tiled-split)
        ln_ts<<<dim3(Mc / 4), dim3(256), 0, stream>>>(x, h_hi, h_lo, gamma1, beta1, 1, m0);

        // 2. qkv = h @ w_qkv + b_qkv  (bf16 row-major)
        mgemm<0><<<dim3(Mc / 128, 3), dim3(256), 0, stream>>>(
            h_hi, h_lo, wth, b_qkv, nullptr, qkvb, nullptr, Mc, 3 * C_, C_, 0);

        // 3. window attention -> a (tiled-split)
        attn_kernel<<<dim3(Mc / WS_), dim3(256), 0, stream>>>(
            qkvb, mask, relb, a_hi, a_lo, m0 / WS_);

        // 4. proj + reverse roll + residual -> d_out holds x1
        mgemm<1><<<dim3(Mc / 128, 1), dim3(256), 0, stream>>>(
            a_hi, a_lo, wth + 49152, b_proj, out, nullptr, x, Mc, C_, C_, m0);

        // 5. m2 = LN2(x1) -> h (reuse)
        ln_ts<<<dim3(Mc / 4), dim3(256), 0, stream>>>(out, h_hi, h_lo, gamma2, beta2, 0, m0);

        // 6+7. d_out += gelu(m2 @ W1 + b1) @ W2 + b2
        mlp_k<<<dim3(Mc / 64), dim3(256), 0, stream>>>(
            h_hi, h_lo, wth + 65536, wth + 131072, b_fc1, b_fc2, out, m0);
    }
}

// Round 6
// 485.158 us; speedup vs baseline: 18.8542x; 1.3106x over previous
//
#include <hip/hip_runtime.h>
#include <math.h>

#define B_ 8
#define L_ 16384
#define C_ 128
#define H_ 4
#define WS_ 64
#define SHIFT_ 32
#define NW_ 256
#define HD_ 32
#define HID_ 512
#define M_ (B_*L_)
#define SCALE_ 0.17677669529663687f
#define EPS_ 1e-5f

using short8 = __attribute__((ext_vector_type(8))) short;
using f32x4  = __attribute__((ext_vector_type(4))) float;
using gas1   = const __attribute__((address_space(1))) unsigned int*;
using las3   = __attribute__((address_space(3))) unsigned int*;
typedef unsigned short ushort_t;

#define GLDS(GP, LP) __builtin_amdgcn_global_load_lds((gas1)(const void*)(GP), \
                                                      (las3)(void*)(LP), 16, 0, 0)

__device__ __forceinline__ f32x4 mfma16(short8 a, short8 b, f32x4 c) {
    return __builtin_amdgcn_mfma_f32_16x16x32_bf16(a, b, c, 0, 0, 0);
}

// RNE float -> bf16
__device__ __forceinline__ ushort_t f2bf(float v)
{
    unsigned u = __float_as_uint(v);
    return (ushort_t)((u + 0x7fff + ((u >> 16) & 1)) >> 16);
}
// split v ~= hi + lo (hi trunc, lo rounds remainder)
__device__ __forceinline__ void bsplit(float v, ushort_t& h, ushort_t& l)
{
    unsigned b = __float_as_uint(v);
    h = (ushort_t)(b >> 16);
    float vh = __uint_as_float(b & 0xffff0000u);
    l = (ushort_t)(__float_as_uint(v - vh) >> 16);
}
__device__ __forceinline__ float bf2f(unsigned s) { return __uint_as_float(s << 16); }

// ---------------------------------------------------------------------------
// LayerNorm -> tiled-split output.  (m,k) -> ((m>>4)*16+(k>>3))*128+(m&15)*8+(k&7)
// ---------------------------------------------------------------------------
__global__ __launch_bounds__(256)
void ln_ts(const float* __restrict__ in, ushort_t* __restrict__ oh,
           ushort_t* __restrict__ ol,
           const float* __restrict__ gamma, const float* __restrict__ beta,
           int do_shift, int m_off)
{
    int m    = blockIdx.x * 4 + (threadIdx.x >> 6);
    int lane = threadIdx.x & 63;
    int gr   = m_off + m;
    int src  = gr;
    if (do_shift) {
        int b = gr >> 14, l = gr & (L_ - 1);
        src = (b << 14) | ((l + SHIFT_) & (L_ - 1));
    }
    const float* row = in + (size_t)src * C_;
    float2 v = *(const float2*)&row[lane * 2];
    float s  = v.x + v.y;
    float ss = v.x * v.x + v.y * v.y;
#pragma unroll
    for (int off = 1; off < 64; off <<= 1) {
        s  += __shfl_xor(s, off);
        ss += __shfl_xor(ss, off);
    }
    float mean = s * (1.f / C_);
    float var  = ss * (1.f / C_) - mean * mean;
    float rstd = rsqrtf(var + EPS_);
    float2 g  = *(const float2*)&gamma[lane * 2];
    float2 bt = *(const float2*)&beta[lane * 2];
    float ox = (v.x - mean) * rstd * g.x + bt.x;
    float oy = (v.y - mean) * rstd * g.y + bt.y;
    int k = lane * 2;
    unsigned idx = (unsigned)((m >> 4) * 16 + (k >> 3)) * 128 + (m & 15) * 8 + (k & 7);
    ushort_t h0, l0, h1, l1;
    bsplit(ox, h0, l0); bsplit(oy, h1, l1);
    *(unsigned*)&oh[idx] = (unsigned)h0 | ((unsigned)h1 << 16);
    *(unsigned*)&ol[idx] = (unsigned)l0 | ((unsigned)l1 << 16);
}

// ---------------------------------------------------------------------------
// Weight convert (hi only, RNE): W[K][N] -> tiled W^T
// qkv[0,49152) proj[49152,65536) fc1[65536,131072) fc2[131072,196608)
// ---------------------------------------------------------------------------
__global__ __launch_bounds__(256)
void wconv(const float* __restrict__ wq, const float* __restrict__ wp,
           const float* __restrict__ w1, const float* __restrict__ w2,
           ushort_t* __restrict__ th)
{
    int e = blockIdx.x * 256 + threadIdx.x;
    const float* W; int K, N, base, local;
    if (e < 49152)       { W = wq; K = 128; N = 384; base = 0;      local = e; }
    else if (e < 65536)  { W = wp; K = 128; N = 128; base = 49152;  local = e - 49152; }
    else if (e < 131072) { W = w1; K = 128; N = 512; base = 65536;  local = e - 65536; }
    else                 { W = w2; K = 512; N = 128; base = 131072; local = e - 131072; }
    int n = local / K, k = local % K;
    int idx = base + ((n >> 4) * (K >> 3) + (k >> 3)) * 128 + (n & 15) * 8 + (k & 7);
    th[idx] = f2bf(W[(size_t)k * N + n]);
}

// ---------------------------------------------------------------------------
// MFMA window attention. One block per window; wave h = head h (no barriers —
// each wave owns its LDS region). qkv bf16 row-major [row][384].
// QK^T: A=Q rows, B=K rows (16 MFMA). Softmax in C/D-layout registers.
// P (normalized, bf16) -> LDS A-frag layout; PV with V^T B-frags (16 MFMA).
// Mask: only window NW-1, fragment-uniform (i^j)&2 pattern. Output tiled-split.
// ---------------------------------------------------------------------------
__global__ __launch_bounds__(256)
void attn_kernel(const ushort_t* __restrict__ qkv, const float* __restrict__ relb,
                 ushort_t* __restrict__ Oh, ushort_t* __restrict__ Ol,
                 int w_off)
{
    __shared__ ushort_t SH[24576];       // per head: QK/P 4096 @ h*4096; Vt 2048 @ 16384+h*2048
    __shared__ float bls[H_][128];
    const int w    = blockIdx.x;
    const int h    = threadIdx.x >> 6;
    const int lane = threadIdx.x & 63;
    ushort_t* QP = SH + h * 4096;        // Q[0,2048) K[2048,4096); later P[0,4096)
    ushort_t* VT = SH + 16384 + h * 2048;

    const ushort_t* base = qkv + (size_t)w * WS_ * 384 + h * HD_;

    // rel_bias column for this head
    bls[h][lane] = relb[lane * H_ + h];
    if (lane < 63) bls[h][lane + 64] = relb[(lane + 64) * H_ + h];

    // stage Q,K tiled: idx(r,k)=((r>>4)*4+(k>>3))*128+(r&15)*8+(k&7)
#pragma unroll
    for (int it = 0; it < 4; ++it) {
        int f = it * 64 + lane;          // 256 16B-chunks per matrix
        int r = f >> 2, oct = f & 3;
        uint4 vq = *(const uint4*)&base[r * 384 + oct * 8];
        uint4 vk = *(const uint4*)&base[r * 384 + C_ + oct * 8];
        int ti = ((r >> 4) * 4 + oct) * 128 + (r & 15) * 8;
        *(uint4*)&QP[ti]        = vq;
        *(uint4*)&QP[2048 + ti] = vk;
    }
    // stage V^T tiled: idx(d,k)=((d>>4)*8+(k>>3))*128+(d&15)*8+(k&7)
#pragma unroll
    for (int it = 0; it < 4; ++it) {
        int f = it * 64 + lane;
        int r = f >> 2, oct = f & 3;     // r = k index, d = oct*8+e
        ushort_t tmp[8];
        *(uint4*)tmp = *(const uint4*)&base[r * 384 + 2 * C_ + oct * 8];
#pragma unroll
        for (int e = 0; e < 8; ++e) {
            int d = oct * 8 + e;
            VT[((d >> 4) * 8 + (r >> 3)) * 128 + (d & 15) * 8 + (r & 7)] = tmp[e];
        }
    }

    // ---- QK^T: 16 MFMA ----
    f32x4 acc[4][4];
    {
        const int lro = (lane >> 4) * 128 + (lane & 15) * 8;
        short8 aq[4], bk[4];
#pragma unroll
        for (int i = 0; i < 4; ++i) aq[i] = *(const short8*)&QP[i * 512 + lro];
#pragma unroll
        for (int j = 0; j < 4; ++j) bk[j] = *(const short8*)&QP[2048 + j * 512 + lro];
        const f32x4 z = {0.f, 0.f, 0.f, 0.f};
#pragma unroll
        for (int i = 0; i < 4; ++i)
#pragma unroll
        for (int j = 0; j < 4; ++j)
            acc[i][j] = mfma16(aq[i], bk[j], z);
    }

    // ---- scale + rel_bias + shift-mask ----
    const int wn = (w_off + w) & (NW_ - 1);
    const bool lastw = (wn == NW_ - 1);
#pragma unroll
    for (int i = 0; i < 4; ++i)
#pragma unroll
    for (int j = 0; j < 4; ++j) {
        const int bidx = i * 16 + (lane >> 4) * 4 - j * 16 - (lane & 15) + 63;
        const float mv = (lastw && ((i ^ j) & 2)) ? -100.f : 0.f;
#pragma unroll
        for (int r = 0; r < 4; ++r)
            acc[i][j][r] = acc[i][j][r] * SCALE_ + bls[h][bidx + r] + mv;
    }
    // ---- softmax (rows: reduce over j-regs + 16-lane column group) ----
    float mx[4][4], sm[4][4];
#pragma unroll
    for (int i = 0; i < 4; ++i)
#pragma unroll
    for (int r = 0; r < 4; ++r) {
        float m = fmaxf(fmaxf(acc[i][0][r], acc[i][1][r]),
                        fmaxf(acc[i][2][r], acc[i][3][r]));
#pragma unroll
        for (int off = 1; off < 16; off <<= 1) m = fmaxf(m, __shfl_xor(m, off));
        mx[i][r] = m;
    }
#pragma unroll
    for (int i = 0; i < 4; ++i)
#pragma unroll
    for (int j = 0; j < 4; ++j)
#pragma unroll
    for (int r = 0; r < 4; ++r)
        acc[i][j][r] = __expf(acc[i][j][r] - mx[i][r]);
#pragma unroll
    for (int i = 0; i < 4; ++i)
#pragma unroll
    for (int r = 0; r < 4; ++r) {
        float s = acc[i][0][r] + acc[i][1][r] + acc[i][2][r] + acc[i][3][r];
#pragma unroll
        for (int off = 1; off < 16; off <<= 1) s += __shfl_xor(s, off);
        sm[i][r] = 1.f / s;
    }
    // ---- P (normalized, bf16) -> LDS A-frag layout [64][64] ----
#pragma unroll
    for (int i = 0; i < 4; ++i)
#pragma unroll
    for (int j = 0; j < 4; ++j) {
        const int kb   = j * 2 + ((lane & 15) >> 3);
        const int koff = lane & 7;
#pragma unroll
        for (int r = 0; r < 4; ++r)
            QP[(i * 8 + kb) * 128 + ((lane >> 4) * 4 + r) * 8 + koff] =
                f2bf(acc[i][j][r] * sm[i][r]);
    }
    // ---- PV: 16 MFMA ----
    f32x4 oacc[4][2] = {};
    {
        short8 vb[2][2];
#pragma unroll
        for (int dp = 0; dp < 2; ++dp)
#pragma unroll
        for (int kk = 0; kk < 2; ++kk)
            vb[dp][kk] = *(const short8*)&VT[(dp * 8 + kk * 4 + (lane >> 4)) * 128 + (lane & 15) * 8];
#pragma unroll
        for (int i = 0; i < 4; ++i)
#pragma unroll
        for (int kk = 0; kk < 2; ++kk) {
            short8 pa = *(const short8*)&QP[(i * 8 + kk * 4 + (lane >> 4)) * 128 + (lane & 15) * 8];
#pragma unroll
            for (int dp = 0; dp < 2; ++dp)
                oacc[i][dp] = mfma16(pa, vb[dp][kk], oacc[i][dp]);
        }
    }
    // ---- store tiled-split ----
    const int gm0 = w * WS_;
#pragma unroll
    for (int i = 0; i < 4; ++i)
#pragma unroll
    for (int dp = 0; dp < 2; ++dp) {
        const int c  = h * HD_ + dp * 16 + (lane & 15);
        const int cb = c >> 3;
#pragma unroll
        for (int r = 0; r < 4; ++r) {
            const int gm = gm0 + i * 16 + (lane >> 4) * 4 + r;
            const size_t idx = ((size_t)(gm >> 4) * 16 + cb) * 128 + (gm & 15) * 8 + (c & 7);
            ushort_t hh, ll; bsplit(oacc[i][dp][r], hh, ll);
            Oh[idx] = hh; Ol[idx] = ll;
        }
    }
}

// ---------------------------------------------------------------------------
// MFMA 2-term GEMM (A split hi/lo, B hi). Tile 128x128, BK=32, dbuf.
// EPI: 0 = bf16 row-major store to Cb; 1 = reverse-roll + X residual -> Cd.
// ---------------------------------------------------------------------------
template<int EPI>
__global__ __launch_bounds__(256, 2)
void mgemm(const ushort_t* __restrict__ Ahi, const ushort_t* __restrict__ Alo,
           const ushort_t* __restrict__ Bhi,
           const float* __restrict__ bias, float* __restrict__ Cd,
           ushort_t* __restrict__ Cb, const float* __restrict__ X,
           int M, int N, int K, int m_off)
{
    __shared__ ushort_t lds[2][3][4096];   // Ahi, Alo, Bhi
    const int t    = threadIdx.x;
    const int lane = t & 63, wid = t >> 6;
    const int wmP  = (wid >> 1) * 4;
    const int wnP  = (wid & 1) * 4;
    const int pm0  = blockIdx.x * 8;
    const int pn0  = blockIdx.y * 8;
    const int lro  = (lane >> 4) * 128 + (lane & 15) * 8;
    const size_t pstr = (size_t)16 * K;

    f32x4 acc[4][4] = {};

#define STAGE(buf, kc) { \
    const size_t ko = (size_t)((kc) >> 3) * 128; \
    _Pragma("unroll") \
    for (int sh = 0; sh < 2; ++sh) { \
        const int f = sh * 2048 + t * 8; \
        const int p = f >> 9, o = f & 511; \
        const size_t ga = (size_t)(pm0 + p) * pstr + ko + o; \
        const size_t gb = (size_t)(pn0 + p) * pstr + ko + o; \
        GLDS(Ahi + ga, &lds[buf][0][f]); \
        GLDS(Alo + ga, &lds[buf][1][f]); \
        GLDS(Bhi + gb, &lds[buf][2][f]); \
    } }

#define COMPUTE(buf) { \
    short8 ah[4], al[4], bh[4]; \
    _Pragma("unroll") for (int i = 0; i < 4; ++i) { \
        ah[i] = *(const short8*)&lds[buf][0][(wmP + i) * 512 + lro]; \
        al[i] = *(const short8*)&lds[buf][1][(wmP + i) * 512 + lro]; \
        bh[i] = *(const short8*)&lds[buf][2][(wnP + i) * 512 + lro]; \
    } \
    _Pragma("unroll") for (int i = 0; i < 4; ++i) \
    _Pragma("unroll") for (int j = 0; j < 4; ++j) { \
        acc[i][j] = mfma16(ah[i], bh[j], acc[i][j]); \
        acc[i][j] = mfma16(al[i], bh[j], acc[i][j]); \
    } }

    const int nst = K >> 5;
    STAGE(0, 0);
    __syncthreads();
    int cur = 0;
    for (int c = 0; c < nst; ++c) {
        if (c + 1 < nst) STAGE(cur ^ 1, (c + 1) << 5);
        COMPUTE(cur);
        __syncthreads();
        cur ^= 1;
    }
#undef STAGE
#undef COMPUTE

    const int m0r = blockIdx.x * 128;
    const int n0  = blockIdx.y * 128;
#pragma unroll
    for (int j = 0; j < 4; ++j) {
        const int col = n0 + (wid & 1) * 64 + j * 16 + (lane & 15);
        const float bv = bias[col];
#pragma unroll
        for (int i = 0; i < 4; ++i) {
#pragma unroll
            for (int r = 0; r < 4; ++r) {
                const int row = m0r + (wid >> 1) * 64 + i * 16 + (lane >> 4) * 4 + r;
                float v = acc[i][j][r] + bv;
                if (EPI == 0) {
                    Cb[(size_t)row * N + col] = f2bf(v);
                } else {
                    int gr = m_off + row;
                    int b = gr >> 14, l = gr & (L_ - 1);
                    size_t dst = ((size_t)((b << 14) | ((l + SHIFT_) & (L_ - 1)))) * C_ + col;
                    Cd[dst] = v + X[dst];
                }
            }
        }
    }
}

// ---------------------------------------------------------------------------
// Fused MLP: out += gelu(m2 @ W1 + b1) @ W2 + b2.
// Block = 64 rows, 256 threads (4 waves, 2x2). HID in 4 quarters of 128.
// LDS: A split 32K + g quarter (bf16, tiled) 16K + W dbuf 16K = 64K.
// fc1 2-term, fc2 1-term (g bf16).
// ---------------------------------------------------------------------------
__global__ __launch_bounds__(256, 2)
void mlp_k(const ushort_t* __restrict__ Ahi, const ushort_t* __restrict__ Alo,
           const ushort_t* __restrict__ W1h, const ushort_t* __restrict__ W2h,
           const float* __restrict__ b1, const float* __restrict__ b2,
           float* __restrict__ Out, int m_off)
{
    __shared__ ushort_t Am[2][8192];    // A hi/lo: 4 panels x 2048
    __shared__ ushort_t Gs[8192];       // g quarter tiled: 4 panels x 2048
    __shared__ ushort_t Wl[2][4096];    // weight chunk dbuf
    const int t    = threadIdx.x;
    const int lane = t & 63, wid = t >> 6;
    const int wm   = (wid >> 1) * 32;   // wave row base (0/32)
    const int wnq  = (wid & 1) * 4;     // wave col-block base (x16)
    const int pm0  = blockIdx.x * 4;    // global A panel base

    // stage A (full K=128, contiguous 8192 ushorts from panel pm0)
    {
        const ushort_t* srcH = Ahi + (size_t)pm0 * 2048;
        const ushort_t* srcL = Alo + (size_t)pm0 * 2048;
#pragma unroll
        for (int sh = 0; sh < 4; ++sh) {
            int f = sh * 2048 + t * 8;
            GLDS(srcH + f, &Am[0][f]);
            GLDS(srcL + f, &Am[1][f]);
        }
    }
    auto stageW1 = [&](int buf, int q, int kk) {
#pragma unroll
        for (int sh = 0; sh < 2; ++sh) {
            int f = sh * 2048 + t * 8;
            int p = f >> 9, o = f & 511;
            GLDS(W1h + (size_t)(q * 8 + p) * 2048 + kk * 512 + o, &Wl[buf][f]);
        }
    };
    auto stageW2 = [&](int buf, int q, int kk) {
#pragma unroll
        for (int sh = 0; sh < 2; ++sh) {
            int f = sh * 2048 + t * 8;
            int p = f >> 9, o = f & 511;
            GLDS(W2h + (size_t)p * 8192 + q * 2048 + kk * 512 + o, &Wl[buf][f]);
        }
    };

    f32x4 acc2[2][4] = {};
    stageW1(0, 0, 0);
    __syncthreads();            // A + W1(0,0) ready
    int buf = 0;

    for (int q = 0; q < 4; ++q) {
        f32x4 acc1[2][4] = {};
        // ---- fc1 quarter (K = 128, 4 steps) ----
#pragma unroll
        for (int kk = 0; kk < 4; ++kk) {
            if (kk < 3) stageW1(buf ^ 1, q, kk + 1);
            else        stageW2(buf ^ 1, q, 0);
            short8 bh[4];
#pragma unroll
            for (int j = 0; j < 4; ++j)
                bh[j] = *(const short8*)&Wl[buf][(wnq + j) * 512 + (lane >> 4) * 128 + (lane & 15) * 8];
#pragma unroll
            for (int i = 0; i < 2; ++i) {
                int ai = ((wid >> 1) * 2 + i) * 2048 + (kk * 4 + (lane >> 4)) * 128 + (lane & 15) * 8;
                short8 ah = *(const short8*)&Am[0][ai];
                short8 al = *(const short8*)&Am[1][ai];
#pragma unroll
                for (int j = 0; j < 4; ++j) {
                    acc1[i][j] = mfma16(ah, bh[j], acc1[i][j]);
                    acc1[i][j] = mfma16(al, bh[j], acc1[i][j]);
                }
            }
            __syncthreads();
            buf ^= 1;
        }
        // ---- GELU + write g to LDS (tiled bf16) ----
#pragma unroll
        for (int i = 0; i < 2; ++i)
#pragma unroll
          for (int j = 0; j < 4; ++j) {
            int kg = (wid & 1) * 64 + j * 16 + (lane & 15);
            float bb = b1[q * 128 + kg];
#pragma unroll
            for (int r = 0; r < 4; ++r) {
                int row = wm + i * 16 + (lane >> 4) * 4 + r;
                float v = acc1[i][j][r] + bb;
                v = 0.5f * v * (1.f + erff(v * 0.70710678118654752f));
                Gs[(row >> 4) * 2048 + (kg >> 3) * 128 + (row & 15) * 8 + (kg & 7)] = f2bf(v);
            }
          }
        __syncthreads();        // g visible; W2(q,0) drained by fc1's last barrier
        // ---- fc2 partial (K = 128, 4 steps), 1-term ----
#pragma unroll
        for (int kk = 0; kk < 4; ++kk) {
            if (kk < 3)      stageW2(buf ^ 1, q, kk + 1);
            else if (q < 3)  stageW1(buf ^ 1, q + 1, 0);
            short8 bh[4];
#pragma unroll
            for (int j = 0; j < 4; ++j)
                bh[j] = *(const short8*)&Wl[buf][(wnq + j) * 512 + (lane >> 4) * 128 + (lane & 15) * 8];
#pragma unroll
            for (int i = 0; i < 2; ++i) {
                int gi = ((wid >> 1) * 2 + i) * 2048 + (kk * 4 + (lane >> 4)) * 128 + (lane & 15) * 8;
                short8 ga = *(const short8*)&Gs[gi];
#pragma unroll
                for (int j = 0; j < 4; ++j)
                    acc2[i][j] = mfma16(ga, bh[j], acc2[i][j]);
            }
            __syncthreads();
            buf ^= 1;
        }
    }
    // ---- epilogue: Out += acc2 + b2 ----
#pragma unroll
    for (int i = 0; i < 2; ++i)
#pragma unroll
      for (int j = 0; j < 4; ++j) {
        int col = (wid & 1) * 64 + j * 16 + (lane & 15);
        float bb = b2[col];
#pragma unroll
        for (int r = 0; r < 4; ++r) {
            int row = blockIdx.x * 64 + wm + i * 16 + (lane >> 4) * 4 + r;
            size_t di = (size_t)(m_off + row) * C_ + col;
            Out[di] += acc2[i][j][r] + bb;
        }
      }
}

// ---------------------------------------------------------------------------
extern "C" void kernel_launch(void* const* d_in, const int* in_sizes, int n_in,
                              void* d_out, int out_size, void* d_ws, size_t ws_size,
                              hipStream_t stream)
{
    const float* x      = (const float*)d_in[0];
    const float* gamma1 = (const float*)d_in[2];
    const float* beta1  = (const float*)d_in[3];
    const float* w_qkv  = (const float*)d_in[4];
    const float* b_qkv  = (const float*)d_in[5];
    const float* relb   = (const float*)d_in[6];
    const float* w_proj = (const float*)d_in[7];
    const float* b_proj = (const float*)d_in[8];
    const float* gamma2 = (const float*)d_in[9];
    const float* beta2  = (const float*)d_in[10];
    const float* w_fc1  = (const float*)d_in[11];
    const float* b_fc1  = (const float*)d_in[12];
    const float* w_fc2  = (const float*)d_in[13];
    const float* b_fc2  = (const float*)d_in[14];
    float* out = (float*)d_out;

    // ws: weights hi 196608 ushort (384KB) + per-chunk dyn = Mc*1792 bytes
    int nch = 8;
    for (int c = 1; c <= 8; c <<= 1) {
        size_t need = 393216 + (size_t)(M_ / c) * 1792;
        if (need <= ws_size) { nch = c; break; }
    }
    const int Mc = M_ / nch;

    ushort_t* wth  = (ushort_t*)d_ws;
    ushort_t* dynp = wth + 196608;
    ushort_t* h_hi = dynp;                         // Mc x 128 (h / m2)
    ushort_t* h_lo = h_hi + (size_t)Mc * C_;
    ushort_t* a_hi = h_lo + (size_t)Mc * C_;
    ushort_t* a_lo = a_hi + (size_t)Mc * C_;
    ushort_t* qkvb = a_lo + (size_t)Mc * C_;       // Mc x 384 bf16

    wconv<<<dim3(768), dim3(256), 0, stream>>>(w_qkv, w_proj, w_fc1, w_fc2, wth);

    for (int ch = 0; ch < nch; ++ch) {
        int m0 = ch * Mc;

        // 1. LN1 + cyclic shift -> h (tiled-split)
        ln_ts<<<dim3(Mc / 4), dim3(256), 0, stream>>>(x, h_hi, h_lo, gamma1, beta1, 1, m0);

        // 2. qkv = h @ w_qkv + b_qkv  (bf16 row-major)
        mgemm<0><<<dim3(Mc / 128, 3), dim3(256), 0, stream>>>(
            h_hi, h_lo, wth, b_qkv, nullptr, qkvb, nullptr, Mc, 3 * C_, C_, 0);

        // 3. MFMA window attention -> a (tiled-split)
        attn_kernel<<<dim3(Mc / WS_), dim3(256), 0, stream>>>(
            qkvb, relb, a_hi, a_lo, m0 / WS_);

        // 4. proj + reverse roll + residual -> d_out holds x1
        mgemm<1><<<dim3(Mc / 128, 1), dim3(256), 0, stream>>>(
            a_hi, a_lo, wth + 49152, b_proj, out, nullptr, x, Mc, C_, C_, m0);

        // 5. m2 = LN2(x1) -> h (reuse)
        ln_ts<<<dim3(Mc / 4), dim3(256), 0, stream>>>(out, h_hi, h_lo, gamma2, beta2, 0, m0);

        // 6+7. d_out += gelu(m2 @ W1 + b1) @ W2 + b2
        mlp_k<<<dim3(Mc / 64), dim3(256), 0, stream>>>(
            h_hi, h_lo, wth + 65536, wth + 131072, b_fc1, b_fc2, out, m0);
    }
}

// Round 9
// 455.944 us; speedup vs baseline: 20.0623x; 1.0641x over previous
//
#include <hip/hip_runtime.h>
#include <math.h>

#define B_ 8
#define L_ 16384
#define C_ 128
#define H_ 4
#define WS_ 64
#define SHIFT_ 32
#define NW_ 256
#define HD_ 32
#define HID_ 512
#define M_ (B_*L_)
#define SCALE_ 0.17677669529663687f
#define EPS_ 1e-5f

using short8 = __attribute__((ext_vector_type(8))) short;
using f32x4  = __attribute__((ext_vector_type(4))) float;
using gas1   = const __attribute__((address_space(1))) unsigned int*;
using las3   = __attribute__((address_space(3))) unsigned int*;
typedef unsigned short ushort_t;

#define GLDS(GP, LP) __builtin_amdgcn_global_load_lds((gas1)(const void*)(GP), \
                                                      (las3)(void*)(LP), 16, 0, 0)

__device__ __forceinline__ f32x4 mfma16(short8 a, short8 b, f32x4 c) {
    return __builtin_amdgcn_mfma_f32_16x16x32_bf16(a, b, c, 0, 0, 0);
}

// RNE float -> bf16
__device__ __forceinline__ ushort_t f2bf(float v)
{
    unsigned u = __float_as_uint(v);
    return (ushort_t)((u + 0x7fff + ((u >> 16) & 1)) >> 16);
}
// split v ~= hi + lo (hi trunc, lo rounds remainder)
__device__ __forceinline__ void bsplit(float v, ushort_t& h, ushort_t& l)
{
    unsigned b = __float_as_uint(v);
    h = (ushort_t)(b >> 16);
    float vh = __uint_as_float(b & 0xffff0000u);
    l = (ushort_t)(__float_as_uint(v - vh) >> 16);
}
__device__ __forceinline__ float bf2f(unsigned s) { return __uint_as_float(s << 16); }

// tanh-form GELU (max |diff| vs exact erf-GELU ~1e-3, << bf16 noise here)
__device__ __forceinline__ float gelu_f(float x)
{
    float u = 1.5957691216057308f * (x + 0.044715f * x * x * x);  // 2*0.7978845608*(...)
    float e = __expf(u);
    float t = 1.f - 2.f / (e + 1.f);       // tanh(u/2 * 2)... = tanh(0.79788*(x+...)*1)
    return 0.5f * x * (1.f + t);
}

// ---------------------------------------------------------------------------
// LayerNorm -> tiled-split output.  (m,k) -> ((m>>4)*16+(k>>3))*128+(m&15)*8+(k&7)
// ---------------------------------------------------------------------------
__global__ __launch_bounds__(256)
void ln_ts(const float* __restrict__ in, ushort_t* __restrict__ oh,
           ushort_t* __restrict__ ol,
           const float* __restrict__ gamma, const float* __restrict__ beta,
           int do_shift, int m_off)
{
    int m    = blockIdx.x * 4 + (threadIdx.x >> 6);
    int lane = threadIdx.x & 63;
    int gr   = m_off + m;
    int src  = gr;
    if (do_shift) {
        int b = gr >> 14, l = gr & (L_ - 1);
        src = (b << 14) | ((l + SHIFT_) & (L_ - 1));
    }
    const float* row = in + (size_t)src * C_;
    float2 v = *(const float2*)&row[lane * 2];
    float s  = v.x + v.y;
    float ss = v.x * v.x + v.y * v.y;
#pragma unroll
    for (int off = 1; off < 64; off <<= 1) {
        s  += __shfl_xor(s, off);
        ss += __shfl_xor(ss, off);
    }
    float mean = s * (1.f / C_);
    float var  = ss * (1.f / C_) - mean * mean;
    float rstd = rsqrtf(var + EPS_);
    float2 g  = *(const float2*)&gamma[lane * 2];
    float2 bt = *(const float2*)&beta[lane * 2];
    float ox = (v.x - mean) * rstd * g.x + bt.x;
    float oy = (v.y - mean) * rstd * g.y + bt.y;
    int k = lane * 2;
    unsigned idx = (unsigned)((m >> 4) * 16 + (k >> 3)) * 128 + (m & 15) * 8 + (k & 7);
    ushort_t h0, l0, h1, l1;
    bsplit(ox, h0, l0); bsplit(oy, h1, l1);
    *(unsigned*)&oh[idx] = (unsigned)h0 | ((unsigned)h1 << 16);
    *(unsigned*)&ol[idx] = (unsigned)l0 | ((unsigned)l1 << 16);
}

// ---------------------------------------------------------------------------
// Weight convert (hi only, RNE): W[K][N] -> tiled W^T
// qkv[0,49152) proj[49152,65536) fc1[65536,131072) fc2[131072,196608)
// ---------------------------------------------------------------------------
__global__ __launch_bounds__(256)
void wconv(const float* __restrict__ wq, const float* __restrict__ wp,
           const float* __restrict__ w1, const float* __restrict__ w2,
           ushort_t* __restrict__ th)
{
    int e = blockIdx.x * 256 + threadIdx.x;
    const float* W; int K, N, base, local;
    if (e < 49152)       { W = wq; K = 128; N = 384; base = 0;      local = e; }
    else if (e < 65536)  { W = wp; K = 128; N = 128; base = 49152;  local = e - 49152; }
    else if (e < 131072) { W = w1; K = 128; N = 512; base = 65536;  local = e - 65536; }
    else                 { W = w2; K = 512; N = 128; base = 131072; local = e - 131072; }
    int n = local / K, k = local % K;
    int idx = base + ((n >> 4) * (K >> 3) + (k >> 3)) * 128 + (n & 15) * 8 + (k & 7);
    th[idx] = f2bf(W[(size_t)k * N + n]);
}

// ---------------------------------------------------------------------------
// MFMA window attention. One block per window; wave h = head h (no barriers —
// each wave owns its LDS region). qkv bf16 row-major [row][384].
// ---------------------------------------------------------------------------
__global__ __launch_bounds__(256)
void attn_kernel(const ushort_t* __restrict__ qkv, const float* __restrict__ relb,
                 ushort_t* __restrict__ Oh, ushort_t* __restrict__ Ol,
                 int w_off)
{
    __shared__ ushort_t SH[24576];       // per head: QK/P 4096 @ h*4096; Vt 2048 @ 16384+h*2048
    __shared__ float bls[H_][128];
    const int w    = blockIdx.x;
    const int h    = threadIdx.x >> 6;
    const int lane = threadIdx.x & 63;
    ushort_t* QP = SH + h * 4096;        // Q[0,2048) K[2048,4096); later P[0,4096)
    ushort_t* VT = SH + 16384 + h * 2048;

    const ushort_t* base = qkv + (size_t)w * WS_ * 384 + h * HD_;

    // rel_bias column for this head
    bls[h][lane] = relb[lane * H_ + h];
    if (lane < 63) bls[h][lane + 64] = relb[(lane + 64) * H_ + h];

    // stage Q,K tiled: idx(r,k)=((r>>4)*4+(k>>3))*128+(r&15)*8+(k&7)
#pragma unroll
    for (int it = 0; it < 4; ++it) {
        int f = it * 64 + lane;          // 256 16B-chunks per matrix
        int r = f >> 2, oct = f & 3;
        uint4 vq = *(const uint4*)&base[r * 384 + oct * 8];
        uint4 vk = *(const uint4*)&base[r * 384 + C_ + oct * 8];
        int ti = ((r >> 4) * 4 + oct) * 128 + (r & 15) * 8;
        *(uint4*)&QP[ti]        = vq;
        *(uint4*)&QP[2048 + ti] = vk;
    }
    // stage V^T tiled: idx(d,k)=((d>>4)*8+(k>>3))*128+(d&15)*8+(k&7)
#pragma unroll
    for (int it = 0; it < 4; ++it) {
        int f = it * 64 + lane;
        int r = f >> 2, oct = f & 3;     // r = k index, d = oct*8+e
        ushort_t tmp[8];
        *(uint4*)tmp = *(const uint4*)&base[r * 384 + 2 * C_ + oct * 8];
#pragma unroll
        for (int e = 0; e < 8; ++e) {
            int d = oct * 8 + e;
            VT[((d >> 4) * 8 + (r >> 3)) * 128 + (d & 15) * 8 + (r & 7)] = tmp[e];
        }
    }

    // ---- QK^T: 16 MFMA ----
    f32x4 acc[4][4];
    {
        const int lro = (lane >> 4) * 128 + (lane & 15) * 8;
        short8 aq[4], bk[4];
#pragma unroll
        for (int i = 0; i < 4; ++i) aq[i] = *(const short8*)&QP[i * 512 + lro];
#pragma unroll
        for (int j = 0; j < 4; ++j) bk[j] = *(const short8*)&QP[2048 + j * 512 + lro];
        const f32x4 z = {0.f, 0.f, 0.f, 0.f};
#pragma unroll
        for (int i = 0; i < 4; ++i)
#pragma unroll
        for (int j = 0; j < 4; ++j)
            acc[i][j] = mfma16(aq[i], bk[j], z);
    }

    // ---- scale + rel_bias + shift-mask ----
    const int wn = (w_off + w) & (NW_ - 1);
    const bool lastw = (wn == NW_ - 1);
#pragma unroll
    for (int i = 0; i < 4; ++i)
#pragma unroll
    for (int j = 0; j < 4; ++j) {
        const int bidx = i * 16 + (lane >> 4) * 4 - j * 16 - (lane & 15) + 63;
        const float mv = (lastw && ((i ^ j) & 2)) ? -100.f : 0.f;
#pragma unroll
        for (int r = 0; r < 4; ++r)
            acc[i][j][r] = acc[i][j][r] * SCALE_ + bls[h][bidx + r] + mv;
    }
    // ---- softmax ----
    float mx[4][4], sm[4][4];
#pragma unroll
    for (int i = 0; i < 4; ++i)
#pragma unroll
    for (int r = 0; r < 4; ++r) {
        float m = fmaxf(fmaxf(acc[i][0][r], acc[i][1][r]),
                        fmaxf(acc[i][2][r], acc[i][3][r]));
#pragma unroll
        for (int off = 1; off < 16; off <<= 1) m = fmaxf(m, __shfl_xor(m, off));
        mx[i][r] = m;
    }
#pragma unroll
    for (int i = 0; i < 4; ++i)
#pragma unroll
    for (int j = 0; j < 4; ++j)
#pragma unroll
    for (int r = 0; r < 4; ++r)
        acc[i][j][r] = __expf(acc[i][j][r] - mx[i][r]);
#pragma unroll
    for (int i = 0; i < 4; ++i)
#pragma unroll
    for (int r = 0; r < 4; ++r) {
        float s = acc[i][0][r] + acc[i][1][r] + acc[i][2][r] + acc[i][3][r];
#pragma unroll
        for (int off = 1; off < 16; off <<= 1) s += __shfl_xor(s, off);
        sm[i][r] = 1.f / s;
    }
    // ---- P (normalized, bf16) -> LDS A-frag layout [64][64] ----
#pragma unroll
    for (int i = 0; i < 4; ++i)
#pragma unroll
    for (int j = 0; j < 4; ++j) {
        const int kb   = j * 2 + ((lane & 15) >> 3);
        const int koff = lane & 7;
#pragma unroll
        for (int r = 0; r < 4; ++r)
            QP[(i * 8 + kb) * 128 + ((lane >> 4) * 4 + r) * 8 + koff] =
                f2bf(acc[i][j][r] * sm[i][r]);
    }
    // ---- PV: 16 MFMA ----
    f32x4 oacc[4][2] = {};
    {
        short8 vb[2][2];
#pragma unroll
        for (int dp = 0; dp < 2; ++dp)
#pragma unroll
        for (int kk = 0; kk < 2; ++kk)
            vb[dp][kk] = *(const short8*)&VT[(dp * 8 + kk * 4 + (lane >> 4)) * 128 + (lane & 15) * 8];
#pragma unroll
        for (int i = 0; i < 4; ++i)
#pragma unroll
        for (int kk = 0; kk < 2; ++kk) {
            short8 pa = *(const short8*)&QP[(i * 8 + kk * 4 + (lane >> 4)) * 128 + (lane & 15) * 8];
#pragma unroll
            for (int dp = 0; dp < 2; ++dp)
                oacc[i][dp] = mfma16(pa, vb[dp][kk], oacc[i][dp]);
        }
    }
    // ---- store tiled-split ----
    const int gm0 = w * WS_;
#pragma unroll
    for (int i = 0; i < 4; ++i)
#pragma unroll
    for (int dp = 0; dp < 2; ++dp) {
        const int c  = h * HD_ + dp * 16 + (lane & 15);
        const int cb = c >> 3;
#pragma unroll
        for (int r = 0; r < 4; ++r) {
            const int gm = gm0 + i * 16 + (lane >> 4) * 4 + r;
            const size_t idx = ((size_t)(gm >> 4) * 16 + cb) * 128 + (gm & 15) * 8 + (c & 7);
            ushort_t hh, ll; bsplit(oacc[i][dp][r], hh, ll);
            Oh[idx] = hh; Ol[idx] = ll;
        }
    }
}

// ---------------------------------------------------------------------------
// MFMA 2-term GEMM (A split hi/lo, B hi). Tile 128x128, BK=32, dbuf.
// EPI: 0 = bf16 row-major store to Cb; 1 = reverse-roll + X residual -> Cd.
// ---------------------------------------------------------------------------
template<int EPI>
__global__ __launch_bounds__(256, 2)
void mgemm(const ushort_t* __restrict__ Ahi, const ushort_t* __restrict__ Alo,
           const ushort_t* __restrict__ Bhi,
           const float* __restrict__ bias, float* __restrict__ Cd,
           ushort_t* __restrict__ Cb, const float* __restrict__ X,
           int M, int N, int K, int m_off)
{
    __shared__ ushort_t lds[2][3][4096];   // Ahi, Alo, Bhi
    const int t    = threadIdx.x;
    const int lane = t & 63, wid = t >> 6;
    const int wmP  = (wid >> 1) * 4;
    const int wnP  = (wid & 1) * 4;
    const int pm0  = blockIdx.x * 8;
    const int pn0  = blockIdx.y * 8;
    const int lro  = (lane >> 4) * 128 + (lane & 15) * 8;
    const size_t pstr = (size_t)16 * K;

    f32x4 acc[4][4] = {};

#define STAGE(buf, kc) { \
    const size_t ko = (size_t)((kc) >> 3) * 128; \
    _Pragma("unroll") \
    for (int sh = 0; sh < 2; ++sh) { \
        const int f = sh * 2048 + t * 8; \
        const int p = f >> 9, o = f & 511; \
        const size_t ga = (size_t)(pm0 + p) * pstr + ko + o; \
        const size_t gb = (size_t)(pn0 + p) * pstr + ko + o; \
        GLDS(Ahi + ga, &lds[buf][0][f]); \
        GLDS(Alo + ga, &lds[buf][1][f]); \
        GLDS(Bhi + gb, &lds[buf][2][f]); \
    } }

#define COMPUTE(buf) { \
    short8 ah[4], al[4], bh[4]; \
    _Pragma("unroll") for (int i = 0; i < 4; ++i) { \
        ah[i] = *(const short8*)&lds[buf][0][(wmP + i) * 512 + lro]; \
        al[i] = *(const short8*)&lds[buf][1][(wmP + i) * 512 + lro]; \
        bh[i] = *(const short8*)&lds[buf][2][(wnP + i) * 512 + lro]; \
    } \
    _Pragma("unroll") for (int i = 0; i < 4; ++i) \
    _Pragma("unroll") for (int j = 0; j < 4; ++j) { \
        acc[i][j] = mfma16(ah[i], bh[j], acc[i][j]); \
        acc[i][j] = mfma16(al[i], bh[j], acc[i][j]); \
    } }

    const int nst = K >> 5;
    STAGE(0, 0);
    __syncthreads();
    int cur = 0;
    for (int c = 0; c < nst; ++c) {
        if (c + 1 < nst) STAGE(cur ^ 1, (c + 1) << 5);
        COMPUTE(cur);
        __syncthreads();
        cur ^= 1;
    }
#undef STAGE
#undef COMPUTE

    const int m0r = blockIdx.x * 128;
    const int n0  = blockIdx.y * 128;
#pragma unroll
    for (int j = 0; j < 4; ++j) {
        const int col = n0 + (wid & 1) * 64 + j * 16 + (lane & 15);
        const float bv = bias[col];
#pragma unroll
        for (int i = 0; i < 4; ++i) {
#pragma unroll
            for (int r = 0; r < 4; ++r) {
                const int row = m0r + (wid >> 1) * 64 + i * 16 + (lane >> 4) * 4 + r;
                float v = acc[i][j][r] + bv;
                if (EPI == 0) {
                    Cb[(size_t)row * N + col] = f2bf(v);
                } else {
                    int gr = m_off + row;
                    int b = gr >> 14, l = gr & (L_ - 1);
                    size_t dst = ((size_t)((b << 14) | ((l + SHIFT_) & (L_ - 1)))) * C_ + col;
                    Cd[dst] = v + X[dst];
                }
            }
        }
    }
}

// ---------------------------------------------------------------------------
// Fused MLP v2: out += gelu(m2 @ W1 + b1) @ W2 + b2.
// Block = 128 rows, 256 threads, 4 waves; wave owns 32 rows x FULL quarter
// width -> g round-trip is wave-private (no barriers). LDS: W1 quarter 32KB
// (single buffer, next-quarter stage hidden under gelu+fc2) + 4x8KB g.
// m2 (split) and W2 fragments are loaded straight from global (L2-hot).
// 2 barriers per quarter. fc1 2-term, fc2 1-term.
// ---------------------------------------------------------------------------
__global__ __launch_bounds__(256, 2)
void mlp_k(const ushort_t* __restrict__ Ahi, const ushort_t* __restrict__ Alo,
           const ushort_t* __restrict__ W1t, const ushort_t* __restrict__ W2t,
           const float* __restrict__ b1, const float* __restrict__ b2,
           float* __restrict__ Out, int m_off)
{
    __shared__ ushort_t Wq[16384];      // W1 quarter: 8 panels x 2048
    __shared__ ushort_t Gs[4][4096];    // per-wave g: 32 rows x 128 k (tiled)
    const int t = threadIdx.x, lane = t & 63, w = t >> 6;
    const int g = lane >> 4, c = lane & 15;
    const int rp0 = blockIdx.x * 8 + w * 2;   // wave's first 16-row panel
    ushort_t* gs = Gs[w];

    // stage W1 quarter 0
#pragma unroll
    for (int it = 0; it < 8; ++it) { int f = it * 2048 + t * 8; GLDS(W1t + f, &Wq[f]); }
    __syncthreads();

    f32x4 acc2[2][8] = {};
    for (int q = 0; q < 4; ++q) {
        f32x4 acc1[2][8] = {};
        // ---- fc1: 32 rows x 128 quarter-cols, K=128 (4 ksteps), 2-term ----
#pragma unroll
        for (int ks = 0; ks < 4; ++ks) {
            short8 mh[2], ml[2], wf[8];
#pragma unroll
            for (int jb = 0; jb < 2; ++jb) {
                size_t ai = (size_t)(rp0 + jb) * 2048 + (ks * 4 + g) * 128 + c * 8;
                mh[jb] = *(const short8*)&Ahi[ai];
                ml[jb] = *(const short8*)&Alo[ai];
            }
#pragma unroll
            for (int cb = 0; cb < 8; ++cb)
                wf[cb] = *(const short8*)&Wq[cb * 2048 + (ks * 4 + g) * 128 + c * 8];
#pragma unroll
            for (int jb = 0; jb < 2; ++jb)
#pragma unroll
            for (int cb = 0; cb < 8; ++cb) {
                acc1[jb][cb] = mfma16(mh[jb], wf[cb], acc1[jb][cb]);
                acc1[jb][cb] = mfma16(ml[jb], wf[cb], acc1[jb][cb]);
            }
        }
        __syncthreads();                 // all waves done reading W1(q)
        if (q < 3) {                     // async stage W1(q+1); hidden under gelu+fc2
            const ushort_t* src = W1t + (q + 1) * 16384;
#pragma unroll
            for (int it = 0; it < 8; ++it) { int f = it * 2048 + t * 8; GLDS(src + f, &Wq[f]); }
        }
        // ---- GELU -> wave-private Gs (A-frag tiled: 2 panels x (16oct x 16row x 8)) ----
#pragma unroll
        for (int jb = 0; jb < 2; ++jb)
#pragma unroll
        for (int cb = 0; cb < 8; ++cb) {
            const int kg = cb * 16 + c;
            const float bb = b1[q * 128 + kg];
#pragma unroll
            for (int r = 0; r < 4; ++r) {
                float v = gelu_f(acc1[jb][cb][r] + bb);
                gs[(jb * 16 + (kg >> 3)) * 128 + (g * 4 + r) * 8 + (kg & 7)] = f2bf(v);
            }
        }
        // ---- fc2 partial: K = this 128-quarter, W2 frags from global ----
#pragma unroll
        for (int ks = 0; ks < 4; ++ks) {
            short8 w2f[8], ga[2];
#pragma unroll
            for (int ocb = 0; ocb < 8; ++ocb) {
                size_t wi = (size_t)ocb * 8192 + (q * 16 + ks * 4 + g) * 128 + c * 8;
                w2f[ocb] = *(const short8*)&W2t[wi];
            }
#pragma unroll
            for (int jb = 0; jb < 2; ++jb)
                ga[jb] = *(const short8*)&gs[(jb * 16 + ks * 4 + g) * 128 + c * 8];
#pragma unroll
            for (int jb = 0; jb < 2; ++jb)
#pragma unroll
            for (int ocb = 0; ocb < 8; ++ocb)
                acc2[jb][ocb] = mfma16(ga[jb], w2f[ocb], acc2[jb][ocb]);
        }
        __syncthreads();                 // drains W1(q+1) stage (vmcnt) for next iter
    }
    // ---- epilogue: Out += acc2 + b2 ----
#pragma unroll
    for (int jb = 0; jb < 2; ++jb)
#pragma unroll
    for (int ocb = 0; ocb < 8; ++ocb) {
        const int col = ocb * 16 + c;
        const float bb = b2[col];
#pragma unroll
        for (int r = 0; r < 4; ++r) {
            const int row = blockIdx.x * 128 + w * 32 + jb * 16 + g * 4 + r;
            size_t di = (size_t)(m_off + row) * C_ + col;
            Out[di] += acc2[jb][ocb][r] + bb;
        }
    }
}

// ---------------------------------------------------------------------------
extern "C" void kernel_launch(void* const* d_in, const int* in_sizes, int n_in,
                              void* d_out, int out_size, void* d_ws, size_t ws_size,
                              hipStream_t stream)
{
    const float* x      = (const float*)d_in[0];
    const float* gamma1 = (const float*)d_in[2];
    const float* beta1  = (const float*)d_in[3];
    const float* w_qkv  = (const float*)d_in[4];
    const float* b_qkv  = (const float*)d_in[5];
    const float* relb   = (const float*)d_in[6];
    const float* w_proj = (const float*)d_in[7];
    const float* b_proj = (const float*)d_in[8];
    const float* gamma2 = (const float*)d_in[9];
    const float* beta2  = (const float*)d_in[10];
    const float* w_fc1  = (const float*)d_in[11];
    const float* b_fc1  = (const float*)d_in[12];
    const float* w_fc2  = (const float*)d_in[13];
    const float* b_fc2  = (const float*)d_in[14];
    float* out = (float*)d_out;

    // ws: weights hi 196608 ushort (384KB) + per-chunk dyn = Mc*1792 bytes
    int nch = 8;
    for (int c = 1; c <= 8; c <<= 1) {
        size_t need = 393216 + (size_t)(M_ / c) * 1792;
        if (need <= ws_size) { nch = c; break; }
    }
    const int Mc = M_ / nch;

    ushort_t* wth  = (ushort_t*)d_ws;
    ushort_t* dynp = wth + 196608;
    ushort_t* h_hi = dynp;                         // Mc x 128 (h / m2)
    ushort_t* h_lo = h_hi + (size_t)Mc * C_;
    ushort_t* a_hi = h_lo + (size_t)Mc * C_;
    ushort_t* a_lo = a_hi + (size_t)Mc * C_;
    ushort_t* qkvb = a_lo + (size_t)Mc * C_;       // Mc x 384 bf16

    wconv<<<dim3(768), dim3(256), 0, stream>>>(w_qkv, w_proj, w_fc1, w_fc2, wth);

    for (int ch = 0; ch < nch; ++ch) {
        int m0 = ch * Mc;

        // 1. LN1 + cyclic shift -> h (tiled-split)
        ln_ts<<<dim3(Mc / 4), dim3(256), 0, stream>>>(x, h_hi, h_lo, gamma1, beta1, 1, m0);

        // 2. qkv = h @ w_qkv + b_qkv  (bf16 row-major)
        mgemm<0><<<dim3(Mc / 128, 3), dim3(256), 0, stream>>>(
            h_hi, h_lo, wth, b_qkv, nullptr, qkvb, nullptr, Mc, 3 * C_, C_, 0);

        // 3. MFMA window attention -> a (tiled-split)
        attn_kernel<<<dim3(Mc / WS_), dim3(256), 0, stream>>>(
            qkvb, relb, a_hi, a_lo, m0 / WS_);

        // 4. proj + reverse roll + residual -> d_out holds x1
        mgemm<1><<<dim3(Mc / 128, 1), dim3(256), 0, stream>>>(
            a_hi, a_lo, wth + 49152, b_proj, out, nullptr, x, Mc, C_, C_, m0);

        // 5. m2 = LN2(x1) -> h (reuse)
        ln_ts<<<dim3(Mc / 4), dim3(256), 0, stream>>>(out, h_hi, h_lo, gamma2, beta2, 0, m0);

        // 6+7. d_out += gelu(m2 @ W1 + b1) @ W2 + b2  (fused, wave-local g)
        mlp_k<<<dim3(Mc / 128), dim3(256), 0, stream>>>(
            h_hi, h_lo, wth + 65536, wth + 131072, b_fc1, b_fc2, out, m0);
    }
}

// Round 11
// 452.893 us; speedup vs baseline: 20.1975x; 1.0067x over previous
//
#include <hip/hip_runtime.h>
#include <math.h>

#define B_ 8
#define L_ 16384
#define C_ 128
#define H_ 4
#define WS_ 64
#define SHIFT_ 32
#define NW_ 256
#define HD_ 32
#define HID_ 512
#define M_ (B_*L_)
#define SCALE_ 0.17677669529663687f
#define EPS_ 1e-5f

using short8 = __attribute__((ext_vector_type(8))) short;
using f32x4  = __attribute__((ext_vector_type(4))) float;
using gas1   = const __attribute__((address_space(1))) unsigned int*;
using las3   = __attribute__((address_space(3))) unsigned int*;
typedef unsigned short ushort_t;

#define GLDS(GP, LP) __builtin_amdgcn_global_load_lds((gas1)(const void*)(GP), \
                                                      (las3)(void*)(LP), 16, 0, 0)

__device__ __forceinline__ f32x4 mfma16(short8 a, short8 b, f32x4 c) {
    return __builtin_amdgcn_mfma_f32_16x16x32_bf16(a, b, c, 0, 0, 0);
}

// RNE float -> bf16
__device__ __forceinline__ ushort_t f2bf(float v)
{
    unsigned u = __float_as_uint(v);
    return (ushort_t)((u + 0x7fff + ((u >> 16) & 1)) >> 16);
}
// split v ~= hi + lo (hi trunc, lo rounds remainder)
__device__ __forceinline__ void bsplit(float v, ushort_t& h, ushort_t& l)
{
    unsigned b = __float_as_uint(v);
    h = (ushort_t)(b >> 16);
    float vh = __uint_as_float(b & 0xffff0000u);
    l = (ushort_t)(__float_as_uint(v - vh) >> 16);
}
__device__ __forceinline__ float bf2f(unsigned s) { return __uint_as_float(s << 16); }

// tanh-form GELU
__device__ __forceinline__ float gelu_f(float x)
{
    float u = 1.5957691216057308f * (x + 0.044715f * x * x * x);
    float e = __expf(u);
    float t = 1.f - 2.f / (e + 1.f);
    return 0.5f * x * (1.f + t);
}

// ---------------------------------------------------------------------------
// LayerNorm -> tiled-split output.  (m,k) -> ((m>>4)*16+(k>>3))*128+(m&15)*8+(k&7)
// ---------------------------------------------------------------------------
__global__ __launch_bounds__(256)
void ln_ts(const float* __restrict__ in, ushort_t* __restrict__ oh,
           ushort_t* __restrict__ ol,
           const float* __restrict__ gamma, const float* __restrict__ beta,
           int do_shift, int m_off)
{
    int m    = blockIdx.x * 4 + (threadIdx.x >> 6);
    int lane = threadIdx.x & 63;
    int gr   = m_off + m;
    int src  = gr;
    if (do_shift) {
        int b = gr >> 14, l = gr & (L_ - 1);
        src = (b << 14) | ((l + SHIFT_) & (L_ - 1));
    }
    const float* row = in + (size_t)src * C_;
    float2 v = *(const float2*)&row[lane * 2];
    float s  = v.x + v.y;
    float ss = v.x * v.x + v.y * v.y;
#pragma unroll
    for (int off = 1; off < 64; off <<= 1) {
        s  += __shfl_xor(s, off);
        ss += __shfl_xor(ss, off);
    }
    float mean = s * (1.f / C_);
    float var  = ss * (1.f / C_) - mean * mean;
    float rstd = rsqrtf(var + EPS_);
    float2 g  = *(const float2*)&gamma[lane * 2];
    float2 bt = *(const float2*)&beta[lane * 2];
    float ox = (v.x - mean) * rstd * g.x + bt.x;
    float oy = (v.y - mean) * rstd * g.y + bt.y;
    int k = lane * 2;
    unsigned idx = (unsigned)((m >> 4) * 16 + (k >> 3)) * 128 + (m & 15) * 8 + (k & 7);
    ushort_t h0, l0, h1, l1;
    bsplit(ox, h0, l0); bsplit(oy, h1, l1);
    *(unsigned*)&oh[idx] = (unsigned)h0 | ((unsigned)h1 << 16);
    *(unsigned*)&ol[idx] = (unsigned)l0 | ((unsigned)l1 << 16);
}

// ---------------------------------------------------------------------------
// Weight convert (hi only, RNE): W[K][N] -> tiled W^T
// qkv[0,49152) proj[49152,65536) fc1[65536,131072) fc2[131072,196608)
// ---------------------------------------------------------------------------
__global__ __launch_bounds__(256)
void wconv(const float* __restrict__ wq, const float* __restrict__ wp,
           const float* __restrict__ w1, const float* __restrict__ w2,
           ushort_t* __restrict__ th)
{
    int e = blockIdx.x * 256 + threadIdx.x;
    const float* W; int K, N, base, local;
    if (e < 49152)       { W = wq; K = 128; N = 384; base = 0;      local = e; }
    else if (e < 65536)  { W = wp; K = 128; N = 128; base = 49152;  local = e - 49152; }
    else if (e < 131072) { W = w1; K = 128; N = 512; base = 65536;  local = e - 65536; }
    else                 { W = w2; K = 512; N = 128; base = 131072; local = e - 131072; }
    int n = local / K, k = local % K;
    int idx = base + ((n >> 4) * (K >> 3) + (k >> 3)) * 128 + (n & 15) * 8 + (k & 7);
    th[idx] = f2bf(W[(size_t)k * N + n]);
}

// ---------------------------------------------------------------------------
// MFMA window attention (unchanged from round 9 green run).
// ---------------------------------------------------------------------------
__global__ __launch_bounds__(256)
void attn_kernel(const ushort_t* __restrict__ qkv, const float* __restrict__ relb,
                 ushort_t* __restrict__ Oh, ushort_t* __restrict__ Ol,
                 int w_off)
{
    __shared__ ushort_t SH[24576];
    __shared__ float bls[H_][128];
    const int w    = blockIdx.x;
    const int h    = threadIdx.x >> 6;
    const int lane = threadIdx.x & 63;
    ushort_t* QP = SH + h * 4096;
    ushort_t* VT = SH + 16384 + h * 2048;

    const ushort_t* base = qkv + (size_t)w * WS_ * 384 + h * HD_;

    bls[h][lane] = relb[lane * H_ + h];
    if (lane < 63) bls[h][lane + 64] = relb[(lane + 64) * H_ + h];

#pragma unroll
    for (int it = 0; it < 4; ++it) {
        int f = it * 64 + lane;
        int r = f >> 2, oct = f & 3;
        uint4 vq = *(const uint4*)&base[r * 384 + oct * 8];
        uint4 vk = *(const uint4*)&base[r * 384 + C_ + oct * 8];
        int ti = ((r >> 4) * 4 + oct) * 128 + (r & 15) * 8;
        *(uint4*)&QP[ti]        = vq;
        *(uint4*)&QP[2048 + ti] = vk;
    }
#pragma unroll
    for (int it = 0; it < 4; ++it) {
        int f = it * 64 + lane;
        int r = f >> 2, oct = f & 3;
        ushort_t tmp[8];
        *(uint4*)tmp = *(const uint4*)&base[r * 384 + 2 * C_ + oct * 8];
#pragma unroll
        for (int e = 0; e < 8; ++e) {
            int d = oct * 8 + e;
            VT[((d >> 4) * 8 + (r >> 3)) * 128 + (d & 15) * 8 + (r & 7)] = tmp[e];
        }
    }

    f32x4 acc[4][4];
    {
        const int lro = (lane >> 4) * 128 + (lane & 15) * 8;
        short8 aq[4], bk[4];
#pragma unroll
        for (int i = 0; i < 4; ++i) aq[i] = *(const short8*)&QP[i * 512 + lro];
#pragma unroll
        for (int j = 0; j < 4; ++j) bk[j] = *(const short8*)&QP[2048 + j * 512 + lro];
        const f32x4 z = {0.f, 0.f, 0.f, 0.f};
#pragma unroll
        for (int i = 0; i < 4; ++i)
#pragma unroll
        for (int j = 0; j < 4; ++j)
            acc[i][j] = mfma16(aq[i], bk[j], z);
    }

    const int wn = (w_off + w) & (NW_ - 1);
    const bool lastw = (wn == NW_ - 1);
#pragma unroll
    for (int i = 0; i < 4; ++i)
#pragma unroll
    for (int j = 0; j < 4; ++j) {
        const int bidx = i * 16 + (lane >> 4) * 4 - j * 16 - (lane & 15) + 63;
        const float mv = (lastw && ((i ^ j) & 2)) ? -100.f : 0.f;
#pragma unroll
        for (int r = 0; r < 4; ++r)
            acc[i][j][r] = acc[i][j][r] * SCALE_ + bls[h][bidx + r] + mv;
    }
    float mx[4][4], sm[4][4];
#pragma unroll
    for (int i = 0; i < 4; ++i)
#pragma unroll
    for (int r = 0; r < 4; ++r) {
        float m = fmaxf(fmaxf(acc[i][0][r], acc[i][1][r]),
                        fmaxf(acc[i][2][r], acc[i][3][r]));
#pragma unroll
        for (int off = 1; off < 16; off <<= 1) m = fmaxf(m, __shfl_xor(m, off));
        mx[i][r] = m;
    }
#pragma unroll
    for (int i = 0; i < 4; ++i)
#pragma unroll
    for (int j = 0; j < 4; ++j)
#pragma unroll
    for (int r = 0; r < 4; ++r)
        acc[i][j][r] = __expf(acc[i][j][r] - mx[i][r]);
#pragma unroll
    for (int i = 0; i < 4; ++i)
#pragma unroll
    for (int r = 0; r < 4; ++r) {
        float s = acc[i][0][r] + acc[i][1][r] + acc[i][2][r] + acc[i][3][r];
#pragma unroll
        for (int off = 1; off < 16; off <<= 1) s += __shfl_xor(s, off);
        sm[i][r] = 1.f / s;
    }
#pragma unroll
    for (int i = 0; i < 4; ++i)
#pragma unroll
    for (int j = 0; j < 4; ++j) {
        const int kb   = j * 2 + ((lane & 15) >> 3);
        const int koff = lane & 7;
#pragma unroll
        for (int r = 0; r < 4; ++r)
            QP[(i * 8 + kb) * 128 + ((lane >> 4) * 4 + r) * 8 + koff] =
                f2bf(acc[i][j][r] * sm[i][r]);
    }
    f32x4 oacc[4][2] = {};
    {
        short8 vb[2][2];
#pragma unroll
        for (int dp = 0; dp < 2; ++dp)
#pragma unroll
        for (int kk = 0; kk < 2; ++kk)
            vb[dp][kk] = *(const short8*)&VT[(dp * 8 + kk * 4 + (lane >> 4)) * 128 + (lane & 15) * 8];
#pragma unroll
        for (int i = 0; i < 4; ++i)
#pragma unroll
        for (int kk = 0; kk < 2; ++kk) {
            short8 pa = *(const short8*)&QP[(i * 8 + kk * 4 + (lane >> 4)) * 128 + (lane & 15) * 8];
#pragma unroll
            for (int dp = 0; dp < 2; ++dp)
                oacc[i][dp] = mfma16(pa, vb[dp][kk], oacc[i][dp]);
        }
    }
    const int gm0 = w * WS_;
#pragma unroll
    for (int i = 0; i < 4; ++i)
#pragma unroll
    for (int dp = 0; dp < 2; ++dp) {
        const int c  = h * HD_ + dp * 16 + (lane & 15);
        const int cb = c >> 3;
#pragma unroll
        for (int r = 0; r < 4; ++r) {
            const int gm = gm0 + i * 16 + (lane >> 4) * 4 + r;
            const size_t idx = ((size_t)(gm >> 4) * 16 + cb) * 128 + (gm & 15) * 8 + (c & 7);
            ushort_t hh, ll; bsplit(oacc[i][dp][r], hh, ll);
            Oh[idx] = hh; Ol[idx] = ll;
        }
    }
}

// ---------------------------------------------------------------------------
// MFMA 2-term GEMM (A split hi/lo, B hi). Tile 128x128, BK=32, dbuf.
// EPI 0: bf16 row-major store to Cb (qkv).
// EPI 1: proj + reverse-roll + X residual -> Cd (x1), FUSED LN2 -> Gh/Gl
//        tiled-split (m2). Requires N==128, grid.y==1.
// ---------------------------------------------------------------------------
template<int EPI>
__global__ __launch_bounds__(256, 2)
void mgemm(const ushort_t* __restrict__ Ahi, const ushort_t* __restrict__ Alo,
           const ushort_t* __restrict__ Bhi,
           const float* __restrict__ bias, float* __restrict__ Cd,
           ushort_t* __restrict__ Cb, const float* __restrict__ X,
           const float* __restrict__ G2, const float* __restrict__ B2,
           ushort_t* __restrict__ Gh, ushort_t* __restrict__ Gl,
           int M, int N, int K, int m_off)
{
    __shared__ ushort_t lds[2][3][4096];   // Ahi, Alo, Bhi
    const int t    = threadIdx.x;
    const int lane = t & 63, wid = t >> 6;
    const int wmP  = (wid >> 1) * 4;
    const int wnP  = (wid & 1) * 4;
    const int pm0  = blockIdx.x * 8;
    const int pn0  = blockIdx.y * 8;
    const int lro  = (lane >> 4) * 128 + (lane & 15) * 8;
    const size_t pstr = (size_t)16 * K;

    f32x4 acc[4][4] = {};

#define STAGE(buf, kc) { \
    const size_t ko = (size_t)((kc) >> 3) * 128; \
    _Pragma("unroll") \
    for (int sh = 0; sh < 2; ++sh) { \
        const int f = sh * 2048 + t * 8; \
        const int p = f >> 9, o = f & 511; \
        const size_t ga = (size_t)(pm0 + p) * pstr + ko + o; \
        const size_t gb = (size_t)(pn0 + p) * pstr + ko + o; \
        GLDS(Ahi + ga, &lds[buf][0][f]); \
        GLDS(Alo + ga, &lds[buf][1][f]); \
        GLDS(Bhi + gb, &lds[buf][2][f]); \
    } }

#define COMPUTE(buf) { \
    short8 ah[4], al[4], bh[4]; \
    _Pragma("unroll") for (int i = 0; i < 4; ++i) { \
        ah[i] = *(const short8*)&lds[buf][0][(wmP + i) * 512 + lro]; \
        al[i] = *(const short8*)&lds[buf][1][(wmP + i) * 512 + lro]; \
        bh[i] = *(const short8*)&lds[buf][2][(wnP + i) * 512 + lro]; \
    } \
    _Pragma("unroll") for (int i = 0; i < 4; ++i) \
    _Pragma("unroll") for (int j = 0; j < 4; ++j) { \
        acc[i][j] = mfma16(ah[i], bh[j], acc[i][j]); \
        acc[i][j] = mfma16(al[i], bh[j], acc[i][j]); \
    } }

    const int nst = K >> 5;
    STAGE(0, 0);
    __syncthreads();
    int cur = 0;
    for (int c = 0; c < nst; ++c) {
        if (c + 1 < nst) STAGE(cur ^ 1, (c + 1) << 5);
        COMPUTE(cur);
        __syncthreads();
        cur ^= 1;
    }
#undef STAGE
#undef COMPUTE

    const int m0r = blockIdx.x * 128;
    const int n0  = blockIdx.y * 128;

    if (EPI == 0) {
#pragma unroll
        for (int j = 0; j < 4; ++j) {
            const int col = n0 + (wid & 1) * 64 + j * 16 + (lane & 15);
            const float bv = bias[col];
#pragma unroll
            for (int i = 0; i < 4; ++i)
#pragma unroll
            for (int r = 0; r < 4; ++r) {
                const int row = m0r + (wid >> 1) * 64 + i * 16 + (lane >> 4) * 4 + r;
                Cb[(size_t)row * N + col] = f2bf(acc[i][j][r] + bv);
            }
        }
    } else {
        // proj + residual + fused LN2. Block owns 128 complete rows (N=128).
        float* sf = (float*)&lds[0][0][0];        // [half][row][2] stats scratch
        float bv[4], g2v[4], b2v[4];
#pragma unroll
        for (int j = 0; j < 4; ++j) {
            const int col = (wid & 1) * 64 + j * 16 + (lane & 15);
            bv[j] = bias[col]; g2v[j] = G2[col]; b2v[j] = B2[col];
        }
        // pass 1: x1 = acc + bias + X(rolled), store x1, accumulate stats
#pragma unroll
        for (int i = 0; i < 4; ++i)
#pragma unroll
        for (int r = 0; r < 4; ++r) {
            const int row = m0r + (wid >> 1) * 64 + i * 16 + (lane >> 4) * 4 + r;
            const int gr = m_off + row;
            const int bb = gr >> 14, l = gr & (L_ - 1);
            const size_t drow = (size_t)((bb << 14) | ((l + SHIFT_) & (L_ - 1)));
            float s = 0.f, ss = 0.f;
#pragma unroll
            for (int j = 0; j < 4; ++j) {
                const int col = (wid & 1) * 64 + j * 16 + (lane & 15);
                float v = acc[i][j][r] + bv[j] + X[drow * C_ + col];
                Cd[drow * C_ + col] = v;
                acc[i][j][r] = v;
                s += v; ss += v * v;
            }
#pragma unroll
            for (int off = 1; off < 16; off <<= 1) {
                s  += __shfl_xor(s, off);
                ss += __shfl_xor(ss, off);
            }
            if ((lane & 15) == 0) {
                const int rl = (wid >> 1) * 64 + i * 16 + (lane >> 4) * 4 + r;
                sf[(wid & 1) * 256 + rl * 2 + 0] = s;
                sf[(wid & 1) * 256 + rl * 2 + 1] = ss;
            }
        }
        __syncthreads();
        // pass 2: combine halves, write m2 tiled-split at unrolled local row
#pragma unroll
        for (int i = 0; i < 4; ++i)
#pragma unroll
        for (int r = 0; r < 4; ++r) {
            const int rl  = (wid >> 1) * 64 + i * 16 + (lane >> 4) * 4 + r;
            const int row = m0r + rl;
            const int gr = m_off + row;
            const int bb = gr >> 14, l = gr & (L_ - 1);
            const int dloc = ((bb << 14) | ((l + SHIFT_) & (L_ - 1))) - m_off;
            const float st  = sf[rl * 2 + 0] + sf[256 + rl * 2 + 0];
            const float sst = sf[rl * 2 + 1] + sf[256 + rl * 2 + 1];
            const float mean = st * (1.f / C_);
            const float var  = sst * (1.f / C_) - mean * mean;
            const float rstd = rsqrtf(var + EPS_);
#pragma unroll
            for (int j = 0; j < 4; ++j) {
                const int col = (wid & 1) * 64 + j * 16 + (lane & 15);
                const float m2 = (acc[i][j][r] - mean) * rstd * g2v[j] + b2v[j];
                ushort_t hh, ll; bsplit(m2, hh, ll);
                const size_t idx = ((size_t)(dloc >> 4) * 16 + (col >> 3)) * 128
                                 + (dloc & 15) * 8 + (col & 7);
                Gh[idx] = hh; Gl[idx] = ll;
            }
        }
    }
}

// ---------------------------------------------------------------------------
// Fused MLP v3: out += gelu(m2 @ W1 + b1) @ W2 + b2.
// Block = 128 rows, 4 waves; wave owns 32 rows x full quarter width.
// A (m2 split) held in REGISTERS for all 4 quarters (64 VGPR).
// LDS: W1 quarter 32KB + W2 quarter 16KB (both GLDS-staged, prefetched a
// phase ahead) + per-wave g half-quarter 4KB x4 = 64KB. 2 barriers/quarter.
// ---------------------------------------------------------------------------
__global__ __launch_bounds__(256, 2)
void mlp_k(const ushort_t* __restrict__ Ahi, const ushort_t* __restrict__ Alo,
           const ushort_t* __restrict__ W1t, const ushort_t* __restrict__ W2t,
           const float* __restrict__ b1, const float* __restrict__ b2,
           float* __restrict__ Out, int m_off)
{
    __shared__ ushort_t Wq[16384];      // W1 quarter: 8 col-panels x 2048
    __shared__ ushort_t W2q[16384];     // W2 quarter: 8 out-panels x 2048
    __shared__ ushort_t Gs[4][2048];    // per-wave g half: 2 panels x 8 oct x 128
    const int t = threadIdx.x, lane = t & 63, w = t >> 6;
    const int g = lane >> 4, c = lane & 15;
    const int rp0 = blockIdx.x * 8 + w * 2;
    ushort_t* gs = Gs[w];

    // A (32 rows x K=128, hi+lo) into registers once
    short8 mh[2][4], ml[2][4];
#pragma unroll
    for (int jb = 0; jb < 2; ++jb)
#pragma unroll
    for (int ks = 0; ks < 4; ++ks) {
        const size_t ai = (size_t)(rp0 + jb) * 2048 + (ks * 4 + g) * 128 + c * 8;
        mh[jb][ks] = *(const short8*)&Ahi[ai];
        ml[jb][ks] = *(const short8*)&Alo[ai];
    }
    // stage W1(0), W2(0)
#pragma unroll
    for (int it = 0; it < 8; ++it) { int f = it * 2048 + t * 8; GLDS(W1t + f, &Wq[f]); }
#pragma unroll
    for (int it = 0; it < 8; ++it) {
        int f = it * 2048 + t * 8; int p = f >> 11, o = f & 2047;
        GLDS(W2t + (size_t)p * 8192 + o, &W2q[f]);
    }
    __syncthreads();

    f32x4 acc2[2][8] = {};
    for (int q = 0; q < 4; ++q) {
        f32x4 acc1[2][8] = {};
        // ---- fc1: pure regs(A) x LDS(W1), 2-term ----
#pragma unroll
        for (int ks = 0; ks < 4; ++ks) {
#pragma unroll
            for (int cb = 0; cb < 8; ++cb) {
                const short8 wf = *(const short8*)&Wq[cb * 2048 + (ks * 4 + g) * 128 + c * 8];
#pragma unroll
                for (int jb = 0; jb < 2; ++jb) {
                    acc1[jb][cb] = mfma16(mh[jb][ks], wf, acc1[jb][cb]);
                    acc1[jb][cb] = mfma16(ml[jb][ks], wf, acc1[jb][cb]);
                }
            }
        }
        __syncthreads();                    // Wq(q) free; W2q(q) landed (prev vmcnt drain)
        if (q < 3) {                        // stage W1(q+1): lands by next barrier
            const ushort_t* src = W1t + (q + 1) * 16384;
#pragma unroll
            for (int it = 0; it < 8; ++it) { int f = it * 2048 + t * 8; GLDS(src + f, &Wq[f]); }
        }
        // ---- per half-quarter: GELU -> wave-private Gs, then fc2 ----
#pragma unroll
        for (int hh = 0; hh < 2; ++hh) {
#pragma unroll
            for (int jb = 0; jb < 2; ++jb)
#pragma unroll
            for (int cb4 = 0; cb4 < 4; ++cb4) {
                const int cb = hh * 4 + cb4;
                const int kg = cb4 * 16 + c;                  // col within half
                const float bb = b1[q * 128 + hh * 64 + kg];
#pragma unroll
                for (int r = 0; r < 4; ++r) {
                    const float v = gelu_f(acc1[jb][cb][r] + bb);
                    gs[(jb * 8 + (kg >> 3)) * 128 + (g * 4 + r) * 8 + (kg & 7)] = f2bf(v);
                }
            }
#pragma unroll
            for (int kk = 0; kk < 2; ++kk) {
                const int ksq = hh * 2 + kk;                  // quarter-local kstep
                short8 ga[2];
#pragma unroll
                for (int jb = 0; jb < 2; ++jb)
                    ga[jb] = *(const short8*)&gs[(jb * 8 + kk * 4 + g) * 128 + c * 8];
#pragma unroll
                for (int ocb = 0; ocb < 8; ++ocb) {
                    const short8 w2f = *(const short8*)&W2q[ocb * 2048 + (ksq * 4 + g) * 128 + c * 8];
#pragma unroll
                    for (int jb = 0; jb < 2; ++jb)
                        acc2[jb][ocb] = mfma16(ga[jb], w2f, acc2[jb][ocb]);
                }
            }
        }
        __syncthreads();                    // W2q(q) free
        if (q < 3) {                        // stage W2(q+1): lands by barrier after fc1(q+1)
#pragma unroll
            for (int it = 0; it < 8; ++it) {
                int f = it * 2048 + t * 8; int p = f >> 11, o = f & 2047;
                GLDS(W2t + (size_t)p * 8192 + (q + 1) * 2048 + o, &W2q[f]);
            }
        }
    }
    // ---- epilogue: Out += acc2 + b2 ----
#pragma unroll
    for (int jb = 0; jb < 2; ++jb)
#pragma unroll
    for (int ocb = 0; ocb < 8; ++ocb) {
        const int col = ocb * 16 + c;
        const float bb = b2[col];
#pragma unroll
        for (int r = 0; r < 4; ++r) {
            const int row = blockIdx.x * 128 + w * 32 + jb * 16 + g * 4 + r;
            size_t di = (size_t)(m_off + row) * C_ + col;
            Out[di] += acc2[jb][ocb][r] + bb;
        }
    }
}

// ---------------------------------------------------------------------------
extern "C" void kernel_launch(void* const* d_in, const int* in_sizes, int n_in,
                              void* d_out, int out_size, void* d_ws, size_t ws_size,
                              hipStream_t stream)
{
    const float* x      = (const float*)d_in[0];
    const float* gamma1 = (const float*)d_in[2];
    const float* beta1  = (const float*)d_in[3];
    const float* w_qkv  = (const float*)d_in[4];
    const float* b_qkv  = (const float*)d_in[5];
    const float* relb   = (const float*)d_in[6];
    const float* w_proj = (const float*)d_in[7];
    const float* b_proj = (const float*)d_in[8];
    const float* gamma2 = (const float*)d_in[9];
    const float* beta2  = (const float*)d_in[10];
    const float* w_fc1  = (const float*)d_in[11];
    const float* b_fc1  = (const float*)d_in[12];
    const float* w_fc2  = (const float*)d_in[13];
    const float* b_fc2  = (const float*)d_in[14];
    float* out = (float*)d_out;

    // ws: weights hi 196608 ushort (384KB) + per-chunk dyn = Mc*1792 bytes
    int nch = 8;
    for (int c = 1; c <= 8; c <<= 1) {
        size_t need = 393216 + (size_t)(M_ / c) * 1792;
        if (need <= ws_size) { nch = c; break; }
    }
    const int Mc = M_ / nch;

    ushort_t* wth  = (ushort_t*)d_ws;
    ushort_t* dynp = wth + 196608;
    ushort_t* h_hi = dynp;                         // Mc x 128 (h / m2)
    ushort_t* h_lo = h_hi + (size_t)Mc * C_;
    ushort_t* a_hi = h_lo + (size_t)Mc * C_;
    ushort_t* a_lo = a_hi + (size_t)Mc * C_;
    ushort_t* qkvb = a_lo + (size_t)Mc * C_;       // Mc x 384 bf16

    wconv<<<dim3(768), dim3(256), 0, stream>>>(w_qkv, w_proj, w_fc1, w_fc2, wth);

    for (int ch = 0; ch < nch; ++ch) {
        int m0 = ch * Mc;

        // 1. LN1 + cyclic shift -> h (tiled-split)
        ln_ts<<<dim3(Mc / 4), dim3(256), 0, stream>>>(x, h_hi, h_lo, gamma1, beta1, 1, m0);

        // 2. qkv = h @ w_qkv + b_qkv  (bf16 row-major)
        mgemm<0><<<dim3(Mc / 128, 3), dim3(256), 0, stream>>>(
            h_hi, h_lo, wth, b_qkv, nullptr, qkvb, nullptr,
            nullptr, nullptr, nullptr, nullptr, Mc, 3 * C_, C_, 0);

        // 3. MFMA window attention -> a (tiled-split)
        attn_kernel<<<dim3(Mc / WS_), dim3(256), 0, stream>>>(
            qkvb, relb, a_hi, a_lo, m0 / WS_);

        // 4. proj + reverse roll + residual -> d_out (x1), fused LN2 -> h (m2)
        mgemm<1><<<dim3(Mc / 128, 1), dim3(256), 0, stream>>>(
            a_hi, a_lo, wth + 49152, b_proj, out, nullptr, x,
            gamma2, beta2, h_hi, h_lo, Mc, C_, C_, m0);

        // 5+6+7. d_out += gelu(m2 @ W1 + b1) @ W2 + b2  (fused, A-in-regs)
        mlp_k<<<dim3(Mc / 128), dim3(256), 0, stream>>>(
            h_hi, h_lo, wth + 65536, wth + 131072, b_fc1, b_fc2, out, m0);
    }
}